// Round 3
// baseline (907.220 us; speedup 1.0000x reference)
//
#include <hip/hip_runtime.h>
#include <hip/hip_cooperative_groups.h>
#include <stdint.h>

#define PARTITIONABLE 1

namespace cg = cooperative_groups;

typedef float f32x4 __attribute__((ext_vector_type(4)));
typedef short bf16x8 __attribute__((ext_vector_type(8)));

namespace {
constexpr int Hh = 56, Ww = 56;
constexpr int HW = Hh * Ww;            // 3136
constexpr int Bsz = 32, Cch = 256;
constexpr int NCH = 69811;             // ceil(25690112*4/1472)
constexpr int HALF = 34906;
constexpr int NB2 = 4096;              // rank buckets (top 12 bits)
constexpr int GB  = 1024;              // cooperative grid blocks (must be co-resident)

// ---- d_out scratch layout (u32 word offsets; consumed before final write) ----
constexpr int SC1_W   = 0;             // u64 x 69824
constexpr int SC2_W   = 139648;
constexpr int BITS1_W = 279296;
constexpr int BITS2_W = 349120;
constexpr int R1_W    = 418944;
constexpr int R2_W    = 488768;
constexpr int HIST1_W = 558592;        // 4096 each, 6 arrays contiguous
constexpr int PRE1_W  = 562688;
constexpr int CNT1_W  = 566784;
constexpr int HIST2_W = 570880;
constexpr int PRE2_W  = 574976;
constexpr int CNT2_W  = 579072;
constexpr int Y_W     = 583168;        // 8192 floats

// ---- d_ws layout ----
constexpr int KEEP_W  = 0;             // 69824 floats
constexpr int MASKV_W = 69824;         // 8192 floats
constexpr int WPACK_W = 78016;         // then bf16 packed weights (ushort)
}

// ---------------- threefry-2x32 (JAX-compatible) ----------------
__host__ __device__ constexpr uint32_t rotl32(uint32_t v, int r) {
  return (v << r) | (v >> (32 - r));
}
__host__ __device__ constexpr uint64_t tf2x32(uint32_t k0, uint32_t k1,
                                              uint32_t x0, uint32_t x1) {
  uint32_t ks2 = k0 ^ k1 ^ 0x1BD11BDAu;
  x0 += k0; x1 += k1;
  {const int R[4]={13,15,26,6};  for(int i=0;i<4;i++){x0+=x1;x1=rotl32(x1,R[i]);x1^=x0;}}
  x0 += k1;  x1 += ks2 + 1u;
  {const int R[4]={17,29,16,24}; for(int i=0;i<4;i++){x0+=x1;x1=rotl32(x1,R[i]);x1^=x0;}}
  x0 += ks2; x1 += k0 + 2u;
  {const int R[4]={13,15,26,6};  for(int i=0;i<4;i++){x0+=x1;x1=rotl32(x1,R[i]);x1^=x0;}}
  x0 += k0;  x1 += k1 + 3u;
  {const int R[4]={17,29,16,24}; for(int i=0;i<4;i++){x0+=x1;x1=rotl32(x1,R[i]);x1^=x0;}}
  x0 += k1;  x1 += ks2 + 4u;
  {const int R[4]={13,15,26,6};  for(int i=0;i<4;i++){x0+=x1;x1=rotl32(x1,R[i]);x1^=x0;}}
  x0 += ks2; x1 += k0 + 5u;
  return ((uint64_t)x0 << 32) | x1;
}

#if PARTITIONABLE
constexpr uint64_t KEY1 = tf2x32(0u, 1234u, 0u, 0u);
constexpr uint64_t SUB1 = tf2x32(0u, 1234u, 0u, 1u);
constexpr uint64_t SUB2 = tf2x32((uint32_t)(KEY1 >> 32), (uint32_t)KEY1, 0u, 1u);
constexpr uint32_t S1H = (uint32_t)(SUB1 >> 32), S1L = (uint32_t)SUB1;
constexpr uint32_t S2H = (uint32_t)(SUB2 >> 32), S2L = (uint32_t)SUB2;
#else
constexpr uint64_t E0 = tf2x32(0u, 1234u, 0u, 2u);
constexpr uint64_t E1 = tf2x32(0u, 1234u, 1u, 3u);
constexpr uint32_t K1H = (uint32_t)(E0 >> 32), K1L = (uint32_t)(E1 >> 32);
constexpr uint64_t F0 = tf2x32(K1H, K1L, 0u, 2u);
constexpr uint64_t F1 = tf2x32(K1H, K1L, 1u, 3u);
constexpr uint32_t S1H = (uint32_t)E0, S1L = (uint32_t)E1;
constexpr uint32_t S2H = (uint32_t)F0, S2L = (uint32_t)F1;
#endif

__device__ __forceinline__ uint32_t rnd_bits(uint32_t kh, uint32_t kl, uint32_t i) {
#if PARTITIONABLE
  uint64_t r = tf2x32(kh, kl, 0u, i);
  return (uint32_t)(r >> 32) ^ (uint32_t)r;
#else
  if (i < (uint32_t)HALF) {
    uint32_t x1 = (i + HALF < (uint32_t)NCH) ? i + HALF : 0u;
    return (uint32_t)(tf2x32(kh, kl, i, x1) >> 32);
  } else {
    return (uint32_t)tf2x32(kh, kl, i - HALF, i);
  }
#endif
}

// ---------------- bf16 helpers ----------------
__device__ __forceinline__ uint32_t f2bf(float f) {   // manual RNE (wpack path)
  uint32_t u = __float_as_uint(f);
  return (u + 0x7FFFu + ((u >> 16) & 1u)) >> 16;
}
__device__ __forceinline__ float bf2f(uint32_t h) {
  return __uint_as_float(h << 16);
}
// single-instruction packed f32x2 -> bf16x2 (RNE), gfx950
__device__ __forceinline__ uint32_t cvtpk(float lo, float hi) {
  uint32_t r;
  asm("v_cvt_pk_bf16_f32 %0, %1, %2" : "=v"(r) : "v"(lo), "v"(hi));
  return r;
}

// ================= fused mask/ymean/scores pipeline (cooperative) =================
// Phases separated by grid.sync():
//  0: zero hists/cnts; weight prepack (independent work)
//  1: threefry bits + bucket histograms
//  2: bucket exclusive scans (blocks 0,1)
//  3: scatter into buckets
//  4: rank within bucket
//  5: keep[] from double-rank (JAX permutation semantics)
//  6: y = mean(masked x) per (b,c) row   [the HBM-heavy phase]
//  7: scores -> maskv (blocks 0..31)
__global__ __launch_bounds__(256, 4) void k_mask(
    uint32_t* bits1, uint32_t* bits2,
    uint32_t* hist1, uint32_t* pre1, uint32_t* cnt1,
    uint32_t* hist2, uint32_t* pre2, uint32_t* cnt2,
    uint64_t* sc1, uint64_t* sc2,
    uint32_t* rk1, uint32_t* rk2,
    const int* plr, float* keep,
    const float* dw, const float* r1w, const float* r2w,
    ushort* wdp, ushort* w1p, ushort* w2p,
    const float* x, float* y,
    const float* fc1, const float* fc2, const float* thr,
    const float* aw, float* maskv) {
  cg::grid_group grid = cg::this_grid();
  __shared__ uint32_t part[256];
  __shared__ float ysh[256];
  __shared__ float hsh[16];
  const int t = threadIdx.x;
  const int tid = blockIdx.x * 256 + t;

  // ---- phase 0: zero counters + weight prepack ----
  if (tid < 6 * NB2) hist1[tid] = 0;               // hist1..cnt2 contiguous
  if (tid >= 32768 && tid < 65536) {
    int s0 = tid - 32768;
    const float* src;
    ushort* dst;
    if (s0 < 8192) {
      int s = s0, ot = s >> 9, ks = (s >> 6) & 7, l = s & 63;
      src = dw + (ot * 16 + (l & 15)) * 256 + ks * 32 + (l >> 4) * 8;
      dst = wdp + s * 8;
    } else if (s0 < 24576) {
      int s = s0 - 8192, ot = s >> 10, ks = (s >> 6) & 15, l = s & 63;
      src = r1w + (ot * 16 + (l & 15)) * 512 + ks * 32 + (l >> 4) * 8;
      dst = w1p + s * 8;
    } else {
      int s = s0 - 24576, ot = s >> 9, ks = (s >> 6) & 7, l = s & 63;
      src = r2w + (ot * 16 + (l & 15)) * 256 + ks * 32 + (l >> 4) * 8;
      dst = w2p + s * 8;
    }
    float4 v0 = *(const float4*)src;
    float4 v1 = *(const float4*)(src + 4);
    uint4 pk;
    pk.x = f2bf(v0.x) | (f2bf(v0.y) << 16);
    pk.y = f2bf(v0.z) | (f2bf(v0.w) << 16);
    pk.z = f2bf(v1.x) | (f2bf(v1.y) << 16);
    pk.w = f2bf(v1.z) | (f2bf(v1.w) << 16);
    *(uint4*)dst = pk;
  }
  grid.sync();

  // ---- phase 1: bits + hist ----
  if (tid < NCH) {
    uint32_t b1 = rnd_bits(S1H, S1L, (uint32_t)tid);
    uint32_t b2 = rnd_bits(S2H, S2L, (uint32_t)tid);
    bits1[tid] = b1; bits2[tid] = b2;
    atomicAdd(&hist1[b1 >> 20], 1u);
    atomicAdd(&hist2[b2 >> 20], 1u);
  }
  grid.sync();

  // ---- phase 2: two bucket scans (block 0 -> set1, block 1 -> set2) ----
  if (blockIdx.x < 2) {
    const uint32_t* h = blockIdx.x ? hist2 : hist1;
    uint32_t* pre = blockIdx.x ? pre2 : pre1;
    uint32_t loc[16];
    uint32_t s = 0;
    #pragma unroll
    for (int j = 0; j < 16; ++j) { loc[j] = h[t * 16 + j]; s += loc[j]; }
    part[t] = s;
    __syncthreads();
    for (int off = 1; off < 256; off <<= 1) {
      uint32_t u = (t >= off) ? part[t - off] : 0u;
      __syncthreads();
      part[t] += u;
      __syncthreads();
    }
    uint32_t run = part[t] - s;
    #pragma unroll
    for (int j = 0; j < 16; ++j) { pre[t * 16 + j] = run; run += loc[j]; }
  }
  grid.sync();

  // ---- phase 3: scatter ----
  if (tid < NCH) {
    uint32_t b = bits1[tid], bk = b >> 20;
    uint32_t pos = pre1[bk] + atomicAdd(&cnt1[bk], 1u);
    sc1[pos] = ((uint64_t)b << 32) | (uint32_t)tid;
    b = bits2[tid]; bk = b >> 20;
    pos = pre2[bk] + atomicAdd(&cnt2[bk], 1u);
    sc2[pos] = ((uint64_t)b << 32) | (uint32_t)tid;
  }
  grid.sync();

  // ---- phase 4: rank ----
  if (tid < NCH) {
    {
      uint32_t b = bits1[tid], bk = b >> 20;
      uint32_t s = pre1[bk], n = hist1[bk];
      uint64_t my = ((uint64_t)b << 32) | (uint32_t)tid;
      uint32_t c = 0;
      for (uint32_t k = 0; k < n; ++k) c += (sc1[s + k] < my) ? 1u : 0u;
      rk1[tid] = s + c;
    }
    {
      uint32_t b = bits2[tid], bk = b >> 20;
      uint32_t s = pre2[bk], n = hist2[bk];
      uint64_t my = ((uint64_t)b << 32) | (uint32_t)tid;
      uint32_t c = 0;
      for (uint32_t k = 0; k < n; ++k) c += (sc2[s + k] < my) ? 1u : 0u;
      rk2[tid] = s + c;
    }
  }
  grid.sync();

  // ---- phase 5: keep ----
  if (tid < NCH) {
    int L = (NCH * plr[0] + 99) / 100;
    keep[tid] = (rk2[rk1[tid]] < (uint32_t)L) ? 0.f : 1.f;
  }
  grid.sync();

  // ---- phase 6: y = mean(masked x) ; 2 rows per wave ----
  {
    int wid = tid >> 6;        // 0..4095
    int lane = t & 63;
    #pragma unroll
    for (int rr = 0; rr < 2; ++rr) {
      int row = wid * 2 + rr;  // 0..8191
      int b = row >> 8, c = row & 255;
      const float4* rowp = (const float4*)(x + (size_t)row * HW);
      float s = 0.f;
      for (int q = lane; q < HW / 4; q += 64) {
        float4 v = rowp[q];
        uint32_t base = (uint32_t)((b * HW + q * 4) * 256 + c);
        s += v.x * keep[base / 368u];
        s += v.y * keep[(base + 256u) / 368u];
        s += v.z * keep[(base + 512u) / 368u];
        s += v.w * keep[(base + 768u) / 368u];
      }
      for (int off = 32; off > 0; off >>= 1) s += __shfl_down(s, off);
      if (lane == 0) y[row] = s * (1.0f / HW);
    }
  }
  grid.sync();

  // ---- phase 7: scores -> maskv (blocks 0..31) ----
  if (blockIdx.x < 32) {
    int b = blockIdx.x;
    ysh[t] = y[b * 256 + t];
    __syncthreads();
    if (t < 16) {
      float a = 0.f;
      for (int c = 0; c < 256; ++c) a += ysh[c] * fc1[t * 256 + c];
      hsh[t] = fmaxf(a, 0.f);
    }
    __syncthreads();
    float s = 0.f;
    #pragma unroll
    for (int j = 0; j < 16; ++j) s += hsh[j] * fc2[t * 16 + j];
    float sc = 1.f / (1.f + expf(-s));
    float m = sc + (float)plr[0] * aw[t] - thr[0];
    maskv[b * 256 + t] = fmaxf(m, 0.f);
  }
}

// ---------------- fused main chain: bf16 MFMA (R0 structure, 8 waves) ----------------
// fragment-linear LDS: element (c,p) at ((c>>5)*4+(p>>4))*512 + ((p&15)+16*((c&31)>>3))*8 + (c&7)
__global__ __launch_bounds__(512, 4) void k_main(
    const float* __restrict__ x, const float* __restrict__ keep,
    const ushort* __restrict__ wdp, const ushort* __restrict__ w1p,
    const ushort* __restrict__ w2p, const float* __restrict__ maskv,
    float* __restrict__ out) {
  __shared__ __align__(16) short XT[16384];   // 32 KB
  __shared__ __align__(16) short ST[16384];   // 32 KB
  int tile = blockIdx.x;
  int bb = tile / 49, hw0 = (tile % 49) * 64;
  int t = threadIdx.x;
  int lane = t & 63, w = t >> 6;
  int l15 = lane & 15, lhi = lane >> 4;

  // ---- stage masked x tile as bf16 fragments: wave w = channels w*32..w*32+31 ----
  {
    const float* xb = x + (size_t)bb * (Cch * HW);
    uint32_t pixb = (uint32_t)(bb * HW + hw0);
    int p = lane;
    uint32_t ia0 = (pixb + (uint32_t)p) * 256u;
    uint32_t k0 = ia0 / 368u;
    uint32_t cstar = 368u * (k0 + 1u) - ia0;   // channels >= cstar use chunk k0+1
    float kp0 = keep[k0];
    float kp1 = keep[k0 + 1];
    const float* xcol = xb + hw0 + p;
    int c0 = w * 32;
    #pragma unroll
    for (int k = 0; k < 4; ++k) {
      uint32_t pw0, pw1, pw2, pw3;
      #pragma unroll
      for (int h = 0; h < 4; ++h) {
        uint32_t ca = (uint32_t)(c0 + k * 8 + h * 2);
        float va = xcol[(size_t)ca * HW] * (ca < cstar ? kp0 : kp1);
        float vb = xcol[(size_t)(ca + 1u) * HW] * ((ca + 1u) < cstar ? kp0 : kp1);
        uint32_t pkv = cvtpk(va, vb);
        if (h == 0) pw0 = pkv; else if (h == 1) pw1 = pkv;
        else if (h == 2) pw2 = pkv; else pw3 = pkv;
      }
      uint4 pk; pk.x = pw0; pk.y = pw1; pk.z = pw2; pk.w = pw3;
      *(uint4*)&XT[(w * 4 + (p >> 4)) * 512 + ((p & 15) + 16 * k) * 8] = pk;
    }
  }
  __syncthreads();

  f32x4 zero4 = {0.f, 0.f, 0.f, 0.f};
  f32x4 acc[2][4];
  int row16a = (lhi >> 1);                // epilogue row helper
  int sub4 = (lhi & 1) * 4;

  // ======== det = Wd @ x ========
  #pragma unroll
  for (int mt = 0; mt < 2; ++mt)
    #pragma unroll
    for (int nt = 0; nt < 4; ++nt) acc[mt][nt] = zero4;
  {
    const ushort* a0p = wdp + ((w * 2 + 0) * 8) * 512 + lane * 8;
    const ushort* a1p = wdp + ((w * 2 + 1) * 8) * 512 + lane * 8;
    bf16x8 a0 = *(const bf16x8*)a0p;
    bf16x8 a1 = *(const bf16x8*)a1p;
    #pragma unroll
    for (int ks = 0; ks < 8; ++ks) {
      bf16x8 na0 = a0, na1 = a1;
      if (ks < 7) {
        na0 = *(const bf16x8*)(a0p + (ks + 1) * 512);
        na1 = *(const bf16x8*)(a1p + (ks + 1) * 512);
      }
      #pragma unroll
      for (int nt = 0; nt < 4; ++nt) {
        bf16x8 b = *(const bf16x8*)&XT[(ks * 4 + nt) * 512 + lane * 8];
        acc[0][nt] = __builtin_amdgcn_mfma_f32_16x16x32_bf16(a0, b, acc[0][nt], 0, 0, 0);
        acc[1][nt] = __builtin_amdgcn_mfma_f32_16x16x32_bf16(a1, b, acc[1][nt], 0, 0, 0);
      }
      a0 = na0; a1 = na1;
    }
  }

  // ---- st = sigmoid(det) * x  (vectorized ushort4 LDS ops) ----
  #pragma unroll
  for (int mt = 0; mt < 2; ++mt) {
    int row16 = mt * 2 + row16a;
    #pragma unroll
    for (int nt = 0; nt < 4; ++nt) {
      int off = (w * 4 + nt) * 512 + (l15 + 16 * row16) * 8 + sub4;
      ushort4 xv = *(const ushort4*)&XT[off];
      float s0 = bf2f(xv.x) / (1.f + __expf(-acc[mt][nt][0]));
      float s1 = bf2f(xv.y) / (1.f + __expf(-acc[mt][nt][1]));
      float s2 = bf2f(xv.z) / (1.f + __expf(-acc[mt][nt][2]));
      float s3 = bf2f(xv.w) / (1.f + __expf(-acc[mt][nt][3]));
      uint2 sv;
      sv.x = cvtpk(s0, s1);
      sv.y = cvtpk(s2, s3);
      *(uint2*)&ST[off] = sv;
    }
  }
  __syncthreads();

  // ======== r1 = relu(W1 @ [x; st]) ========
  f32x4 acc2[2][4];
  #pragma unroll
  for (int mt = 0; mt < 2; ++mt)
    #pragma unroll
    for (int nt = 0; nt < 4; ++nt) acc2[mt][nt] = zero4;
  {
    const ushort* a0p = w1p + ((w * 2 + 0) * 16) * 512 + lane * 8;
    const ushort* a1p = w1p + ((w * 2 + 1) * 16) * 512 + lane * 8;
    bf16x8 a0 = *(const bf16x8*)a0p;
    bf16x8 a1 = *(const bf16x8*)a1p;
    #pragma unroll
    for (int ks = 0; ks < 16; ++ks) {
      bf16x8 na0 = a0, na1 = a1;
      if (ks < 15) {
        na0 = *(const bf16x8*)(a0p + (ks + 1) * 512);
        na1 = *(const bf16x8*)(a1p + (ks + 1) * 512);
      }
      const short* bsrc = (ks < 8) ? &XT[(ks * 4) * 512] : &ST[((ks - 8) * 4) * 512];
      #pragma unroll
      for (int nt = 0; nt < 4; ++nt) {
        bf16x8 b = *(const bf16x8*)&bsrc[nt * 512 + lane * 8];
        acc2[0][nt] = __builtin_amdgcn_mfma_f32_16x16x32_bf16(a0, b, acc2[0][nt], 0, 0, 0);
        acc2[1][nt] = __builtin_amdgcn_mfma_f32_16x16x32_bf16(a1, b, acc2[1][nt], 0, 0, 0);
      }
      a0 = na0; a1 = na1;
    }
  }
  __syncthreads();   // all rec1 LDS reads complete before overwriting XT

  // ---- write r1 = relu(acc2) into XT ----
  #pragma unroll
  for (int mt = 0; mt < 2; ++mt) {
    int row16 = mt * 2 + row16a;
    #pragma unroll
    for (int nt = 0; nt < 4; ++nt) {
      int off = (w * 4 + nt) * 512 + (l15 + 16 * row16) * 8 + sub4;
      uint2 rv;
      rv.x = cvtpk(fmaxf(acc2[mt][nt][0], 0.f), fmaxf(acc2[mt][nt][1], 0.f));
      rv.y = cvtpk(fmaxf(acc2[mt][nt][2], 0.f), fmaxf(acc2[mt][nt][3], 0.f));
      *(uint2*)&XT[off] = rv;
    }
  }
  __syncthreads();

  // ======== out = (W2 @ r1) * mask ========
  #pragma unroll
  for (int mt = 0; mt < 2; ++mt)
    #pragma unroll
    for (int nt = 0; nt < 4; ++nt) acc[mt][nt] = zero4;
  {
    const ushort* a0p = w2p + ((w * 2 + 0) * 8) * 512 + lane * 8;
    const ushort* a1p = w2p + ((w * 2 + 1) * 8) * 512 + lane * 8;
    bf16x8 a0 = *(const bf16x8*)a0p;
    bf16x8 a1 = *(const bf16x8*)a1p;
    #pragma unroll
    for (int ks = 0; ks < 8; ++ks) {
      bf16x8 na0 = a0, na1 = a1;
      if (ks < 7) {
        na0 = *(const bf16x8*)(a0p + (ks + 1) * 512);
        na1 = *(const bf16x8*)(a1p + (ks + 1) * 512);
      }
      #pragma unroll
      for (int nt = 0; nt < 4; ++nt) {
        bf16x8 b = *(const bf16x8*)&XT[(ks * 4 + nt) * 512 + lane * 8];
        acc[0][nt] = __builtin_amdgcn_mfma_f32_16x16x32_bf16(a0, b, acc[0][nt], 0, 0, 0);
        acc[1][nt] = __builtin_amdgcn_mfma_f32_16x16x32_bf16(a1, b, acc[1][nt], 0, 0, 0);
      }
      a0 = na0; a1 = na1;
    }
  }

  // ---- final: scale by mask, store fp32 ----
  #pragma unroll
  for (int mt = 0; mt < 2; ++mt)
    #pragma unroll
    for (int r = 0; r < 4; ++r) {
      int o = w * 32 + mt * 16 + 4 * lhi + r;
      float m = maskv[bb * 256 + o];
      float* orow = out + (size_t)(bb * 256 + o) * HW + hw0;
      #pragma unroll
      for (int nt = 0; nt < 4; ++nt)
        orow[nt * 16 + l15] = acc[mt][nt][r] * m;
    }
}

extern "C" void kernel_launch(void* const* d_in, const int* in_sizes, int n_in,
                              void* d_out, int out_size, void* d_ws, size_t ws_size,
                              hipStream_t stream) {
  const float* x   = (const float*)d_in[0];
  const float* fc1 = (const float*)d_in[1];
  const float* fc2 = (const float*)d_in[2];
  const float* thr = (const float*)d_in[3];
  const float* dw  = (const float*)d_in[4];
  const float* r1w = (const float*)d_in[5];
  const float* r2w = (const float*)d_in[6];
  const float* aw  = (const float*)d_in[7];
  const int*   plr = (const int*)d_in[8];

  float*    out = (float*)d_out;
  uint32_t* ob  = (uint32_t*)d_out;
  float*    ws  = (float*)d_ws;

  uint64_t* sc1   = (uint64_t*)(ob + SC1_W);
  uint64_t* sc2   = (uint64_t*)(ob + SC2_W);
  uint32_t* bits1 = ob + BITS1_W;
  uint32_t* bits2 = ob + BITS2_W;
  uint32_t* rk1   = ob + R1_W;
  uint32_t* rk2   = ob + R2_W;
  uint32_t* hist1 = ob + HIST1_W;
  uint32_t* pre1  = ob + PRE1_W;
  uint32_t* cnt1  = ob + CNT1_W;
  uint32_t* hist2 = ob + HIST2_W;
  uint32_t* pre2  = ob + PRE2_W;
  uint32_t* cnt2  = ob + CNT2_W;
  float*    yv    = (float*)(ob + Y_W);

  float*  keep  = ws + KEEP_W;
  float*  maskv = ws + MASKV_W;
  ushort* wdp   = (ushort*)(ws + WPACK_W);
  ushort* w1p   = wdp + 65536;
  ushort* w2p   = w1p + 131072;

  void* args[] = {
    (void*)&bits1, (void*)&bits2,
    (void*)&hist1, (void*)&pre1, (void*)&cnt1,
    (void*)&hist2, (void*)&pre2, (void*)&cnt2,
    (void*)&sc1, (void*)&sc2,
    (void*)&rk1, (void*)&rk2,
    (void*)&plr, (void*)&keep,
    (void*)&dw, (void*)&r1w, (void*)&r2w,
    (void*)&wdp, (void*)&w1p, (void*)&w2p,
    (void*)&x, (void*)&yv,
    (void*)&fc1, (void*)&fc2, (void*)&thr,
    (void*)&aw, (void*)&maskv
  };
  hipLaunchCooperativeKernel((const void*)k_mask, dim3(GB), dim3(256),
                             args, 0, stream);
  k_main<<<1568, 512, 0, stream>>>(x, keep, wdp, w1p, w2p, maskv, out);
}

// Round 4
// 230.132 us; speedup vs baseline: 3.9422x; 3.9422x over previous
//
#include <hip/hip_runtime.h>
#include <stdint.h>

#define PARTITIONABLE 1

typedef float f32x4 __attribute__((ext_vector_type(4)));
typedef short bf16x8 __attribute__((ext_vector_type(8)));

namespace {
constexpr int Hh = 56, Ww = 56;
constexpr int HW = Hh * Ww;            // 3136
constexpr int Bsz = 32, Cch = 256;
constexpr int NCH = 69811;             // ceil(25690112*4/1472)
constexpr int HALF = 34906;
constexpr int NB2 = 4096;              // rank buckets (top 12 bits)

// ---- d_out scratch layout (u32 word offsets; consumed before final write) ----
constexpr int SC1_W   = 0;             // u64 x 69824
constexpr int SC2_W   = 139648;
constexpr int BITS1_W = 279296;
constexpr int BITS2_W = 349120;
constexpr int R1_W    = 418944;
constexpr int R2_W    = 488768;
constexpr int HIST1_W = 558592;        // 4096 each, 6 arrays contiguous
constexpr int PRE1_W  = 562688;
constexpr int CNT1_W  = 566784;
constexpr int HIST2_W = 570880;
constexpr int PRE2_W  = 574976;
constexpr int CNT2_W  = 579072;
constexpr int DONE_W  = 583168;        // 32 u32 arrival counters (memset covers)
constexpr int Y_W     = 583200;        // 8192 floats

// ---- d_ws layout ----
constexpr int KEEP_W  = 0;             // 69824 floats
constexpr int MASKV_W = 69824;         // 8192 floats
constexpr int WPACK_W = 78016;         // then bf16 packed weights (ushort)
}

// ---------------- threefry-2x32 (JAX-compatible) ----------------
__host__ __device__ constexpr uint32_t rotl32(uint32_t v, int r) {
  return (v << r) | (v >> (32 - r));
}
__host__ __device__ constexpr uint64_t tf2x32(uint32_t k0, uint32_t k1,
                                              uint32_t x0, uint32_t x1) {
  uint32_t ks2 = k0 ^ k1 ^ 0x1BD11BDAu;
  x0 += k0; x1 += k1;
  {const int R[4]={13,15,26,6};  for(int i=0;i<4;i++){x0+=x1;x1=rotl32(x1,R[i]);x1^=x0;}}
  x0 += k1;  x1 += ks2 + 1u;
  {const int R[4]={17,29,16,24}; for(int i=0;i<4;i++){x0+=x1;x1=rotl32(x1,R[i]);x1^=x0;}}
  x0 += ks2; x1 += k0 + 2u;
  {const int R[4]={13,15,26,6};  for(int i=0;i<4;i++){x0+=x1;x1=rotl32(x1,R[i]);x1^=x0;}}
  x0 += k0;  x1 += k1 + 3u;
  {const int R[4]={17,29,16,24}; for(int i=0;i<4;i++){x0+=x1;x1=rotl32(x1,R[i]);x1^=x0;}}
  x0 += k1;  x1 += ks2 + 4u;
  {const int R[4]={13,15,26,6};  for(int i=0;i<4;i++){x0+=x1;x1=rotl32(x1,R[i]);x1^=x0;}}
  x0 += ks2; x1 += k0 + 5u;
  return ((uint64_t)x0 << 32) | x1;
}

#if PARTITIONABLE
constexpr uint64_t KEY1 = tf2x32(0u, 1234u, 0u, 0u);
constexpr uint64_t SUB1 = tf2x32(0u, 1234u, 0u, 1u);
constexpr uint64_t SUB2 = tf2x32((uint32_t)(KEY1 >> 32), (uint32_t)KEY1, 0u, 1u);
constexpr uint32_t S1H = (uint32_t)(SUB1 >> 32), S1L = (uint32_t)SUB1;
constexpr uint32_t S2H = (uint32_t)(SUB2 >> 32), S2L = (uint32_t)SUB2;
#else
constexpr uint64_t E0 = tf2x32(0u, 1234u, 0u, 2u);
constexpr uint64_t E1 = tf2x32(0u, 1234u, 1u, 3u);
constexpr uint32_t K1H = (uint32_t)(E0 >> 32), K1L = (uint32_t)(E1 >> 32);
constexpr uint64_t F0 = tf2x32(K1H, K1L, 0u, 2u);
constexpr uint64_t F1 = tf2x32(K1H, K1L, 1u, 3u);
constexpr uint32_t S1H = (uint32_t)E0, S1L = (uint32_t)E1;
constexpr uint32_t S2H = (uint32_t)F0, S2L = (uint32_t)F1;
#endif

__device__ __forceinline__ uint32_t rnd_bits(uint32_t kh, uint32_t kl, uint32_t i) {
#if PARTITIONABLE
  uint64_t r = tf2x32(kh, kl, 0u, i);
  return (uint32_t)(r >> 32) ^ (uint32_t)r;
#else
  if (i < (uint32_t)HALF) {
    uint32_t x1 = (i + HALF < (uint32_t)NCH) ? i + HALF : 0u;
    return (uint32_t)(tf2x32(kh, kl, i, x1) >> 32);
  } else {
    return (uint32_t)tf2x32(kh, kl, i - HALF, i);
  }
#endif
}

// ---------------- bf16 helpers ----------------
__device__ __forceinline__ uint32_t f2bf(float f) {   // manual RNE (wpack path)
  uint32_t u = __float_as_uint(f);
  return (u + 0x7FFFu + ((u >> 16) & 1u)) >> 16;
}
__device__ __forceinline__ float bf2f(uint32_t h) {
  return __uint_as_float(h << 16);
}
// single-instruction packed f32x2 -> bf16x2 (RNE), gfx950
__device__ __forceinline__ uint32_t cvtpk(float lo, float hi) {
  uint32_t r;
  asm("v_cvt_pk_bf16_f32 %0, %1, %2" : "=v"(r) : "v"(lo), "v"(hi));
  return r;
}

// ---------------- mask pipeline ----------------
__global__ void k_bits(uint32_t* bits1, uint32_t* bits2,
                       uint32_t* hist1, uint32_t* hist2) {
  int i = blockIdx.x * 256 + threadIdx.x;
  if (i >= NCH) return;
  uint32_t b1 = rnd_bits(S1H, S1L, (uint32_t)i);
  uint32_t b2 = rnd_bits(S2H, S2L, (uint32_t)i);
  bits1[i] = b1; bits2[i] = b2;
  atomicAdd(&hist1[b1 >> 20], 1u);
  atomicAdd(&hist2[b2 >> 20], 1u);
}

// both scans in one launch: block 0 -> (h1,p1), block 1 -> (h2,p2)
__global__ __launch_bounds__(1024) void k_scan2(const uint32_t* h1, uint32_t* p1o,
                                                const uint32_t* h2, uint32_t* p2o) {
  const uint32_t* h = blockIdx.x ? h2 : h1;
  uint32_t* pre = blockIdx.x ? p2o : p1o;
  __shared__ uint32_t part[1024];
  int t = threadIdx.x;
  uint4 v = *(const uint4*)&h[t * 4];
  uint32_t s = v.x + v.y + v.z + v.w;
  part[t] = s;
  __syncthreads();
  for (int off = 1; off < 1024; off <<= 1) {
    uint32_t u = (t >= off) ? part[t - off] : 0u;
    __syncthreads();
    part[t] += u;
    __syncthreads();
  }
  uint32_t run = part[t] - s;
  uint4 o;
  o.x = run; o.y = run + v.x; o.z = o.y + v.y; o.w = o.z + v.z;
  *(uint4*)&pre[t * 4] = o;
}

__global__ void k_scatter2(const uint32_t* bits1, const uint32_t* pre1,
                           uint32_t* cnt1, uint64_t* sc1,
                           const uint32_t* bits2, const uint32_t* pre2,
                           uint32_t* cnt2, uint64_t* sc2) {
  int blk = blockIdx.x;
  bool second = blk >= 273;
  const uint32_t* bits = second ? bits2 : bits1;
  const uint32_t* pre  = second ? pre2  : pre1;
  uint32_t* cnt = second ? cnt2 : cnt1;
  uint64_t* sc  = second ? sc2  : sc1;
  int i = (second ? blk - 273 : blk) * 256 + threadIdx.x;
  if (i >= NCH) return;
  uint32_t b = bits[i], bk = b >> 20;
  uint32_t pos = pre[bk] + atomicAdd(&cnt[bk], 1u);
  sc[pos] = ((uint64_t)b << 32) | (uint32_t)i;
}

__global__ void k_rank2(const uint32_t* bits1, const uint32_t* pre1,
                        const uint32_t* hist1, const uint64_t* sc1, uint32_t* rk1,
                        const uint32_t* bits2, const uint32_t* pre2,
                        const uint32_t* hist2, const uint64_t* sc2, uint32_t* rk2) {
  int blk = blockIdx.x;
  bool second = blk >= 273;
  const uint32_t* bits = second ? bits2 : bits1;
  const uint32_t* pre  = second ? pre2  : pre1;
  const uint32_t* hist = second ? hist2 : hist1;
  const uint64_t* sc   = second ? sc2   : sc1;
  uint32_t* rnk = second ? rk2 : rk1;
  int i = (second ? blk - 273 : blk) * 256 + threadIdx.x;
  if (i >= NCH) return;
  uint32_t b = bits[i], bk = b >> 20;
  uint32_t s = pre[bk], n = hist[bk];
  uint64_t my = ((uint64_t)b << 32) | (uint32_t)i;
  uint32_t c = 0;
  for (uint32_t k = 0; k < n; ++k) c += (sc[s + k] < my) ? 1u : 0u;
  rnk[i] = s + c;
}

// keep + weight prepack fused (wpack part has no deps on rank)
__global__ void k_keepwpack(const uint32_t* r1, const uint32_t* r2,
                            const int* plr, float* keep,
                            const float* __restrict__ dw,
                            const float* __restrict__ r1w,
                            const float* __restrict__ r2w,
                            ushort* __restrict__ wdp, ushort* __restrict__ w1p,
                            ushort* __restrict__ w2p) {
  int blk = blockIdx.x;
  if (blk < 273) {
    int j = blk * 256 + threadIdx.x;
    if (j >= NCH) return;
    int L = (NCH * plr[0] + 99) / 100;
    keep[j] = (r2[r1[j]] < (uint32_t)L) ? 0.f : 1.f;
    return;
  }
  int tid = (blk - 273) * 256 + threadIdx.x;   // 32768 slots
  const float* src;
  ushort* dst;
  if (tid < 8192) {
    int s = tid, ot = s >> 9, ks = (s >> 6) & 7, l = s & 63;
    src = dw + (ot * 16 + (l & 15)) * 256 + ks * 32 + (l >> 4) * 8;
    dst = wdp + s * 8;
  } else if (tid < 24576) {
    int s = tid - 8192, ot = s >> 10, ks = (s >> 6) & 15, l = s & 63;
    src = r1w + (ot * 16 + (l & 15)) * 512 + ks * 32 + (l >> 4) * 8;
    dst = w1p + s * 8;
  } else {
    int s = tid - 24576, ot = s >> 9, ks = (s >> 6) & 7, l = s & 63;
    src = r2w + (ot * 16 + (l & 15)) * 256 + ks * 32 + (l >> 4) * 8;
    dst = w2p + s * 8;
  }
  float4 v0 = *(const float4*)src;
  float4 v1 = *(const float4*)(src + 4);
  uint4 pk;
  pk.x = f2bf(v0.x) | (f2bf(v0.y) << 16);
  pk.y = f2bf(v0.z) | (f2bf(v0.w) << 16);
  pk.z = f2bf(v1.x) | (f2bf(v1.y) << 16);
  pk.w = f2bf(v1.z) | (f2bf(v1.w) << 16);
  *(uint4*)dst = pk;
}

// ---------- y = mean(masked x) + fused scores via per-batch arrival counter ----------
// 1024 blocks = 32 batches x 32 channel-octets. Last-arriving block of a batch
// (atomicAdd(done[b]) == 31) computes scores -> maskv for that batch. No spinning.
__global__ __launch_bounds__(256) void k_ymean2(
    const float* __restrict__ x, const float* __restrict__ keep,
    float* __restrict__ y, uint32_t* __restrict__ done,
    const float* __restrict__ fc1, const float* __restrict__ fc2,
    const float* __restrict__ thr, const float* __restrict__ aw,
    const int* __restrict__ plr, float* __restrict__ maskv) {
  int blk = blockIdx.x;
  int b = blk >> 5, sub = blk & 31;
  int t = threadIdx.x, lane = t & 63, v = t >> 6;
  #pragma unroll
  for (int cc = 0; cc < 2; ++cc) {
    int c = sub * 8 + v * 2 + cc;
    int row = b * 256 + c;
    const float4* rowp = (const float4*)(x + (size_t)row * HW);
    float s = 0.f;
    for (int q = lane; q < HW / 4; q += 64) {
      float4 vv = rowp[q];
      uint32_t base = (uint32_t)((b * HW + q * 4) * 256 + c);
      s += vv.x * keep[base / 368u];
      s += vv.y * keep[(base + 256u) / 368u];
      s += vv.z * keep[(base + 512u) / 368u];
      s += vv.w * keep[(base + 768u) / 368u];
    }
    for (int off = 32; off > 0; off >>= 1) s += __shfl_down(s, off);
    if (lane == 0) y[row] = s * (1.0f / HW);
  }
  // arrival: make y writes visible, then count in
  __threadfence();
  __syncthreads();
  __shared__ int lastf;
  if (t == 0) {
    uint32_t ret = atomicAdd(&done[b], 1u);
    lastf = (ret == 31u) ? 1 : 0;
  }
  __syncthreads();
  if (!lastf) return;
  __threadfence();   // acquire side
  __shared__ float ysh[256];
  __shared__ float hsh[16];
  ysh[t] = ((volatile const float*)y)[b * 256 + t];
  __syncthreads();
  if (t < 16) {
    float a = 0.f;
    for (int c = 0; c < 256; ++c) a += ysh[c] * fc1[t * 256 + c];
    hsh[t] = fmaxf(a, 0.f);
  }
  __syncthreads();
  float s = 0.f;
  #pragma unroll
  for (int j = 0; j < 16; ++j) s += hsh[j] * fc2[t * 16 + j];
  float sc = 1.f / (1.f + expf(-s));
  float m = sc + (float)plr[0] * aw[t] - thr[0];
  maskv[b * 256 + t] = fmaxf(m, 0.f);
}

// ---------------- fused main chain: bf16 MFMA (8 waves, 4ch-group x 2px-half) ----------------
// fragment-linear LDS: element (c,p) at ((c>>5)*4+(p>>4))*512 + ((p&15)+16*((c&31)>>3))*8 + (c&7)
// Wave w: g = w>>1 owns channels [g*64, g*64+64) (A-tiles 4g..4g+3);
//         h = w&1 owns pixel half nt in {2h, 2h+1}.
// Each B-frag read feeds 4 MFMAs (was 2) -> LDS read traffic halved vs R0.
__global__ __launch_bounds__(512, 4) void k_main(
    const float* __restrict__ x, const float* __restrict__ keep,
    const ushort* __restrict__ wdp, const ushort* __restrict__ w1p,
    const ushort* __restrict__ w2p, const float* __restrict__ maskv,
    float* __restrict__ out) {
  __shared__ __align__(16) short XT[16384];   // 32 KB
  __shared__ __align__(16) short ST[16384];   // 32 KB
  int tile = blockIdx.x;
  int bb = tile / 49, hw0 = (tile % 49) * 64;
  int t = threadIdx.x;
  int lane = t & 63, w = t >> 6;
  int l15 = lane & 15, lhi = lane >> 4;
  int g = w >> 1, h = w & 1;

  // ---- stage masked x tile as bf16 fragments: wave w = channels w*32..w*32+31 ----
  {
    const float* xb = x + (size_t)bb * (Cch * HW);
    uint32_t pixb = (uint32_t)(bb * HW + hw0);
    int p = lane;
    uint32_t ia0 = (pixb + (uint32_t)p) * 256u;
    uint32_t k0 = ia0 / 368u;
    uint32_t cstar = 368u * (k0 + 1u) - ia0;   // channels >= cstar use chunk k0+1
    float kp0 = keep[k0];
    float kp1 = keep[k0 + 1];
    const float* xcol = xb + hw0 + p;
    int c0 = w * 32;
    #pragma unroll
    for (int k = 0; k < 4; ++k) {
      uint32_t pw0, pw1, pw2, pw3;
      #pragma unroll
      for (int hh = 0; hh < 4; ++hh) {
        uint32_t ca = (uint32_t)(c0 + k * 8 + hh * 2);
        float va = xcol[(size_t)ca * HW] * (ca < cstar ? kp0 : kp1);
        float vb = xcol[(size_t)(ca + 1u) * HW] * ((ca + 1u) < cstar ? kp0 : kp1);
        uint32_t pkv = cvtpk(va, vb);
        if (hh == 0) pw0 = pkv; else if (hh == 1) pw1 = pkv;
        else if (hh == 2) pw2 = pkv; else pw3 = pkv;
      }
      uint4 pk; pk.x = pw0; pk.y = pw1; pk.z = pw2; pk.w = pw3;
      *(uint4*)&XT[(w * 4 + (p >> 4)) * 512 + ((p & 15) + 16 * k) * 8] = pk;
    }
  }
  __syncthreads();

  f32x4 zero4 = {0.f, 0.f, 0.f, 0.f};
  f32x4 acc[4][2];
  int row16a = (lhi >> 1);
  int sub4 = (lhi & 1) * 4;

  // ======== det = Wd @ x ========
  #pragma unroll
  for (int mt = 0; mt < 4; ++mt)
    #pragma unroll
    for (int n2 = 0; n2 < 2; ++n2) acc[mt][n2] = zero4;
  {
    const ushort* ap = wdp + (size_t)(g * 32) * 512 + lane * 8;   // tile stride 8*512
    bf16x8 a[4], na[4];
    #pragma unroll
    for (int mt = 0; mt < 4; ++mt) a[mt] = *(const bf16x8*)(ap + (size_t)mt * 8 * 512);
    #pragma unroll
    for (int ks = 0; ks < 8; ++ks) {
      #pragma unroll
      for (int mt = 0; mt < 4; ++mt)
        na[mt] = (ks < 7) ? *(const bf16x8*)(ap + (size_t)(mt * 8 + ks + 1) * 512) : a[mt];
      #pragma unroll
      for (int n2 = 0; n2 < 2; ++n2) {
        bf16x8 b = *(const bf16x8*)&XT[(ks * 4 + 2 * h + n2) * 512 + lane * 8];
        #pragma unroll
        for (int mt = 0; mt < 4; ++mt)
          acc[mt][n2] = __builtin_amdgcn_mfma_f32_16x16x32_bf16(a[mt], b, acc[mt][n2], 0, 0, 0);
      }
      #pragma unroll
      for (int mt = 0; mt < 4; ++mt) a[mt] = na[mt];
    }
  }

  // ---- st = sigmoid(det) * x -> ST (XT untouched; no barrier needed) ----
  #pragma unroll
  for (int mt = 0; mt < 4; ++mt) {
    int cg32 = 2 * g + (mt >> 1);
    int row16 = (mt & 1) * 2 + row16a;
    #pragma unroll
    for (int n2 = 0; n2 < 2; ++n2) {
      int nt = 2 * h + n2;
      int off = (cg32 * 4 + nt) * 512 + (l15 + 16 * row16) * 8 + sub4;
      ushort4 xv = *(const ushort4*)&XT[off];
      float s0 = bf2f(xv.x) / (1.f + __expf(-acc[mt][n2][0]));
      float s1 = bf2f(xv.y) / (1.f + __expf(-acc[mt][n2][1]));
      float s2 = bf2f(xv.z) / (1.f + __expf(-acc[mt][n2][2]));
      float s3 = bf2f(xv.w) / (1.f + __expf(-acc[mt][n2][3]));
      uint2 sv;
      sv.x = cvtpk(s0, s1);
      sv.y = cvtpk(s2, s3);
      *(uint2*)&ST[off] = sv;
    }
  }
  __syncthreads();

  // ======== r1 = relu(W1 @ [x; st]) ========
  f32x4 acc2[4][2];
  #pragma unroll
  for (int mt = 0; mt < 4; ++mt)
    #pragma unroll
    for (int n2 = 0; n2 < 2; ++n2) acc2[mt][n2] = zero4;
  {
    const ushort* ap = w1p + (size_t)(g * 64) * 512 + lane * 8;   // tile stride 16*512
    bf16x8 a[4], na[4];
    #pragma unroll
    for (int mt = 0; mt < 4; ++mt) a[mt] = *(const bf16x8*)(ap + (size_t)mt * 16 * 512);
    #pragma unroll
    for (int ks = 0; ks < 16; ++ks) {
      #pragma unroll
      for (int mt = 0; mt < 4; ++mt)
        na[mt] = (ks < 15) ? *(const bf16x8*)(ap + (size_t)(mt * 16 + ks + 1) * 512) : a[mt];
      const short* bsrc = (ks < 8) ? &XT[(ks * 4) * 512] : &ST[((ks - 8) * 4) * 512];
      #pragma unroll
      for (int n2 = 0; n2 < 2; ++n2) {
        bf16x8 b = *(const bf16x8*)&bsrc[(2 * h + n2) * 512 + lane * 8];
        #pragma unroll
        for (int mt = 0; mt < 4; ++mt)
          acc2[mt][n2] = __builtin_amdgcn_mfma_f32_16x16x32_bf16(a[mt], b, acc2[mt][n2], 0, 0, 0);
      }
      #pragma unroll
      for (int mt = 0; mt < 4; ++mt) a[mt] = na[mt];
    }
  }
  __syncthreads();   // all rec1 LDS reads complete before overwriting XT

  // ---- write r1 = relu(acc2) into XT ----
  #pragma unroll
  for (int mt = 0; mt < 4; ++mt) {
    int cg32 = 2 * g + (mt >> 1);
    int row16 = (mt & 1) * 2 + row16a;
    #pragma unroll
    for (int n2 = 0; n2 < 2; ++n2) {
      int nt = 2 * h + n2;
      int off = (cg32 * 4 + nt) * 512 + (l15 + 16 * row16) * 8 + sub4;
      uint2 rv;
      rv.x = cvtpk(fmaxf(acc2[mt][n2][0], 0.f), fmaxf(acc2[mt][n2][1], 0.f));
      rv.y = cvtpk(fmaxf(acc2[mt][n2][2], 0.f), fmaxf(acc2[mt][n2][3], 0.f));
      *(uint2*)&XT[off] = rv;
    }
  }
  __syncthreads();

  // ======== out = (W2 @ r1) * mask ========
  #pragma unroll
  for (int mt = 0; mt < 4; ++mt)
    #pragma unroll
    for (int n2 = 0; n2 < 2; ++n2) acc[mt][n2] = zero4;
  {
    const ushort* ap = w2p + (size_t)(g * 32) * 512 + lane * 8;   // tile stride 8*512
    bf16x8 a[4], na[4];
    #pragma unroll
    for (int mt = 0; mt < 4; ++mt) a[mt] = *(const bf16x8*)(ap + (size_t)mt * 8 * 512);
    #pragma unroll
    for (int ks = 0; ks < 8; ++ks) {
      #pragma unroll
      for (int mt = 0; mt < 4; ++mt)
        na[mt] = (ks < 7) ? *(const bf16x8*)(ap + (size_t)(mt * 8 + ks + 1) * 512) : a[mt];
      #pragma unroll
      for (int n2 = 0; n2 < 2; ++n2) {
        bf16x8 b = *(const bf16x8*)&XT[(ks * 4 + 2 * h + n2) * 512 + lane * 8];
        #pragma unroll
        for (int mt = 0; mt < 4; ++mt)
          acc[mt][n2] = __builtin_amdgcn_mfma_f32_16x16x32_bf16(a[mt], b, acc[mt][n2], 0, 0, 0);
      }
      #pragma unroll
      for (int mt = 0; mt < 4; ++mt) a[mt] = na[mt];
    }
  }

  // ---- final: scale by mask, store fp32 ----
  #pragma unroll
  for (int mt = 0; mt < 4; ++mt)
    #pragma unroll
    for (int r = 0; r < 4; ++r) {
      int o = g * 64 + mt * 16 + 4 * lhi + r;
      float m = maskv[bb * 256 + o];
      float* orow = out + (size_t)(bb * 256 + o) * HW + hw0;
      #pragma unroll
      for (int n2 = 0; n2 < 2; ++n2)
        orow[(2 * h + n2) * 16 + l15] = acc[mt][n2][r] * m;
    }
}

extern "C" void kernel_launch(void* const* d_in, const int* in_sizes, int n_in,
                              void* d_out, int out_size, void* d_ws, size_t ws_size,
                              hipStream_t stream) {
  const float* x   = (const float*)d_in[0];
  const float* fc1 = (const float*)d_in[1];
  const float* fc2 = (const float*)d_in[2];
  const float* thr = (const float*)d_in[3];
  const float* dw  = (const float*)d_in[4];
  const float* r1w = (const float*)d_in[5];
  const float* r2w = (const float*)d_in[6];
  const float* aw  = (const float*)d_in[7];
  const int*   plr = (const int*)d_in[8];

  float*    out = (float*)d_out;
  uint32_t* ob  = (uint32_t*)d_out;
  float*    ws  = (float*)d_ws;

  uint64_t* sc1   = (uint64_t*)(ob + SC1_W);
  uint64_t* sc2   = (uint64_t*)(ob + SC2_W);
  uint32_t* bits1 = ob + BITS1_W;
  uint32_t* bits2 = ob + BITS2_W;
  uint32_t* rk1   = ob + R1_W;
  uint32_t* rk2   = ob + R2_W;
  uint32_t* hist1 = ob + HIST1_W;
  uint32_t* pre1  = ob + PRE1_W;
  uint32_t* cnt1  = ob + CNT1_W;
  uint32_t* hist2 = ob + HIST2_W;
  uint32_t* pre2  = ob + PRE2_W;
  uint32_t* cnt2  = ob + CNT2_W;
  uint32_t* done  = ob + DONE_W;
  float*    yv    = (float*)(ob + Y_W);

  float*  keep  = ws + KEEP_W;
  float*  maskv = ws + MASKV_W;
  ushort* wdp   = (ushort*)(ws + WPACK_W);
  ushort* w1p   = wdp + 65536;
  ushort* w2p   = w1p + 131072;

  // zero hist/pre/cnt (6*NB2 u32) + done (32 u32, contiguous after cnt2)
  hipMemsetAsync((void*)(ob + HIST1_W), 0, (size_t)6 * NB2 * 4 + 128, stream);

  dim3 blk(256);
  k_bits<<<273, blk, 0, stream>>>(bits1, bits2, hist1, hist2);
  k_scan2<<<2, 1024, 0, stream>>>(hist1, pre1, hist2, pre2);
  k_scatter2<<<546, blk, 0, stream>>>(bits1, pre1, cnt1, sc1,
                                      bits2, pre2, cnt2, sc2);
  k_rank2<<<546, blk, 0, stream>>>(bits1, pre1, hist1, sc1, rk1,
                                   bits2, pre2, hist2, sc2, rk2);
  k_keepwpack<<<401, blk, 0, stream>>>(rk1, rk2, plr, keep, dw, r1w, r2w,
                                       wdp, w1p, w2p);
  k_ymean2<<<1024, blk, 0, stream>>>(x, keep, yv, done, fc1, fc2, thr, aw,
                                     plr, maskv);
  k_main<<<1568, 512, 0, stream>>>(x, keep, wdp, w1p, w2p, maskv, out);
}

// Round 5
// 162.362 us; speedup vs baseline: 5.5876x; 1.4174x over previous
//
#include <hip/hip_runtime.h>
#include <stdint.h>

#define PARTITIONABLE 1

typedef float f32x4 __attribute__((ext_vector_type(4)));
typedef short bf16x8 __attribute__((ext_vector_type(8)));

namespace {
constexpr int Hh = 56, Ww = 56;
constexpr int HW = Hh * Ww;            // 3136
constexpr int Bsz = 32, Cch = 256;
constexpr int NCH = 69811;             // ceil(25690112*4/1472)
constexpr int HALF = 34906;
constexpr int NB2 = 4096;              // rank buckets (top 12 bits)

// ---- d_out scratch layout (u32 word offsets; consumed before final write) ----
constexpr int SC1_W   = 0;             // u64 x 69824
constexpr int SC2_W   = 139648;
constexpr int BITS1_W = 279296;
constexpr int BITS2_W = 349120;
constexpr int R1_W    = 418944;
constexpr int R2_W    = 488768;
constexpr int HIST1_W = 558592;        // 4096 each, 6 arrays contiguous
constexpr int PRE1_W  = 562688;
constexpr int CNT1_W  = 566784;
constexpr int HIST2_W = 570880;
constexpr int PRE2_W  = 574976;
constexpr int CNT2_W  = 579072;
constexpr int Y_W     = 583168;        // 8192 floats

// ---- d_ws layout ----
constexpr int KEEP_W  = 0;             // 69824 floats
constexpr int MASKV_W = 69824;         // 8192 floats
constexpr int WPACK_W = 78016;         // then bf16 packed weights (ushort)
}

// ---------------- threefry-2x32 (JAX-compatible) ----------------
__host__ __device__ constexpr uint32_t rotl32(uint32_t v, int r) {
  return (v << r) | (v >> (32 - r));
}
__host__ __device__ constexpr uint64_t tf2x32(uint32_t k0, uint32_t k1,
                                              uint32_t x0, uint32_t x1) {
  uint32_t ks2 = k0 ^ k1 ^ 0x1BD11BDAu;
  x0 += k0; x1 += k1;
  {const int R[4]={13,15,26,6};  for(int i=0;i<4;i++){x0+=x1;x1=rotl32(x1,R[i]);x1^=x0;}}
  x0 += k1;  x1 += ks2 + 1u;
  {const int R[4]={17,29,16,24}; for(int i=0;i<4;i++){x0+=x1;x1=rotl32(x1,R[i]);x1^=x0;}}
  x0 += ks2; x1 += k0 + 2u;
  {const int R[4]={13,15,26,6};  for(int i=0;i<4;i++){x0+=x1;x1=rotl32(x1,R[i]);x1^=x0;}}
  x0 += k0;  x1 += k1 + 3u;
  {const int R[4]={17,29,16,24}; for(int i=0;i<4;i++){x0+=x1;x1=rotl32(x1,R[i]);x1^=x0;}}
  x0 += k1;  x1 += ks2 + 4u;
  {const int R[4]={13,15,26,6};  for(int i=0;i<4;i++){x0+=x1;x1=rotl32(x1,R[i]);x1^=x0;}}
  x0 += ks2; x1 += k0 + 5u;
  return ((uint64_t)x0 << 32) | x1;
}

#if PARTITIONABLE
constexpr uint64_t KEY1 = tf2x32(0u, 1234u, 0u, 0u);
constexpr uint64_t SUB1 = tf2x32(0u, 1234u, 0u, 1u);
constexpr uint64_t SUB2 = tf2x32((uint32_t)(KEY1 >> 32), (uint32_t)KEY1, 0u, 1u);
constexpr uint32_t S1H = (uint32_t)(SUB1 >> 32), S1L = (uint32_t)SUB1;
constexpr uint32_t S2H = (uint32_t)(SUB2 >> 32), S2L = (uint32_t)SUB2;
#else
constexpr uint64_t E0 = tf2x32(0u, 1234u, 0u, 2u);
constexpr uint64_t E1 = tf2x32(0u, 1234u, 1u, 3u);
constexpr uint32_t K1H = (uint32_t)(E0 >> 32), K1L = (uint32_t)(E1 >> 32);
constexpr uint64_t F0 = tf2x32(K1H, K1L, 0u, 2u);
constexpr uint64_t F1 = tf2x32(K1H, K1L, 1u, 3u);
constexpr uint32_t S1H = (uint32_t)E0, S1L = (uint32_t)E1;
constexpr uint32_t S2H = (uint32_t)F0, S2L = (uint32_t)F1;
#endif

__device__ __forceinline__ uint32_t rnd_bits(uint32_t kh, uint32_t kl, uint32_t i) {
#if PARTITIONABLE
  uint64_t r = tf2x32(kh, kl, 0u, i);
  return (uint32_t)(r >> 32) ^ (uint32_t)r;
#else
  if (i < (uint32_t)HALF) {
    uint32_t x1 = (i + HALF < (uint32_t)NCH) ? i + HALF : 0u;
    return (uint32_t)(tf2x32(kh, kl, i, x1) >> 32);
  } else {
    return (uint32_t)tf2x32(kh, kl, i - HALF, i);
  }
#endif
}

// ---------------- bf16 helpers ----------------
__device__ __forceinline__ uint32_t f2bf(float f) {   // manual RNE (wpack path)
  uint32_t u = __float_as_uint(f);
  return (u + 0x7FFFu + ((u >> 16) & 1u)) >> 16;
}
__device__ __forceinline__ float bf2f(uint32_t h) {
  return __uint_as_float(h << 16);
}
// single-instruction packed f32x2 -> bf16x2 (RNE), gfx950
__device__ __forceinline__ uint32_t cvtpk(float lo, float hi) {
  uint32_t r;
  asm("v_cvt_pk_bf16_f32 %0, %1, %2" : "=v"(r) : "v"(lo), "v"(hi));
  return r;
}

// ---------------- mask pipeline ----------------
__global__ void k_bits(uint32_t* bits1, uint32_t* bits2,
                       uint32_t* hist1, uint32_t* hist2) {
  int i = blockIdx.x * 256 + threadIdx.x;
  if (i >= NCH) return;
  uint32_t b1 = rnd_bits(S1H, S1L, (uint32_t)i);
  uint32_t b2 = rnd_bits(S2H, S2L, (uint32_t)i);
  bits1[i] = b1; bits2[i] = b2;
  atomicAdd(&hist1[b1 >> 20], 1u);
  atomicAdd(&hist2[b2 >> 20], 1u);
}

// both scans in one launch: block 0 -> (h1,p1), block 1 -> (h2,p2)
__global__ __launch_bounds__(1024) void k_scan2(const uint32_t* h1, uint32_t* p1o,
                                                const uint32_t* h2, uint32_t* p2o) {
  const uint32_t* h = blockIdx.x ? h2 : h1;
  uint32_t* pre = blockIdx.x ? p2o : p1o;
  __shared__ uint32_t part[1024];
  int t = threadIdx.x;
  uint4 v = *(const uint4*)&h[t * 4];
  uint32_t s = v.x + v.y + v.z + v.w;
  part[t] = s;
  __syncthreads();
  for (int off = 1; off < 1024; off <<= 1) {
    uint32_t u = (t >= off) ? part[t - off] : 0u;
    __syncthreads();
    part[t] += u;
    __syncthreads();
  }
  uint32_t run = part[t] - s;
  uint4 o;
  o.x = run; o.y = run + v.x; o.z = o.y + v.y; o.w = o.z + v.z;
  *(uint4*)&pre[t * 4] = o;
}

__global__ void k_scatter2(const uint32_t* bits1, const uint32_t* pre1,
                           uint32_t* cnt1, uint64_t* sc1,
                           const uint32_t* bits2, const uint32_t* pre2,
                           uint32_t* cnt2, uint64_t* sc2) {
  int blk = blockIdx.x;
  bool second = blk >= 273;
  const uint32_t* bits = second ? bits2 : bits1;
  const uint32_t* pre  = second ? pre2  : pre1;
  uint32_t* cnt = second ? cnt2 : cnt1;
  uint64_t* sc  = second ? sc2  : sc1;
  int i = (second ? blk - 273 : blk) * 256 + threadIdx.x;
  if (i >= NCH) return;
  uint32_t b = bits[i], bk = b >> 20;
  uint32_t pos = pre[bk] + atomicAdd(&cnt[bk], 1u);
  sc[pos] = ((uint64_t)b << 32) | (uint32_t)i;
}

__global__ void k_rank2(const uint32_t* bits1, const uint32_t* pre1,
                        const uint32_t* hist1, const uint64_t* sc1, uint32_t* rk1,
                        const uint32_t* bits2, const uint32_t* pre2,
                        const uint32_t* hist2, const uint64_t* sc2, uint32_t* rk2) {
  int blk = blockIdx.x;
  bool second = blk >= 273;
  const uint32_t* bits = second ? bits2 : bits1;
  const uint32_t* pre  = second ? pre2  : pre1;
  const uint32_t* hist = second ? hist2 : hist1;
  const uint64_t* sc   = second ? sc2   : sc1;
  uint32_t* rnk = second ? rk2 : rk1;
  int i = (second ? blk - 273 : blk) * 256 + threadIdx.x;
  if (i >= NCH) return;
  uint32_t b = bits[i], bk = b >> 20;
  uint32_t s = pre[bk], n = hist[bk];
  uint64_t my = ((uint64_t)b << 32) | (uint32_t)i;
  uint32_t c = 0;
  for (uint32_t k = 0; k < n; ++k) c += (sc[s + k] < my) ? 1u : 0u;
  rnk[i] = s + c;
}

// keep + weight prepack fused (wpack part has no deps on rank)
__global__ void k_keepwpack(const uint32_t* r1, const uint32_t* r2,
                            const int* plr, float* keep,
                            const float* __restrict__ dw,
                            const float* __restrict__ r1w,
                            const float* __restrict__ r2w,
                            ushort* __restrict__ wdp, ushort* __restrict__ w1p,
                            ushort* __restrict__ w2p) {
  int blk = blockIdx.x;
  if (blk < 273) {
    int j = blk * 256 + threadIdx.x;
    if (j >= NCH) return;
    int L = (NCH * plr[0] + 99) / 100;
    keep[j] = (r2[r1[j]] < (uint32_t)L) ? 0.f : 1.f;
    return;
  }
  int tid = (blk - 273) * 256 + threadIdx.x;   // 32768 slots
  const float* src;
  ushort* dst;
  if (tid < 8192) {
    int s = tid, ot = s >> 9, ks = (s >> 6) & 7, l = s & 63;
    src = dw + (ot * 16 + (l & 15)) * 256 + ks * 32 + (l >> 4) * 8;
    dst = wdp + s * 8;
  } else if (tid < 24576) {
    int s = tid - 8192, ot = s >> 10, ks = (s >> 6) & 15, l = s & 63;
    src = r1w + (ot * 16 + (l & 15)) * 512 + ks * 32 + (l >> 4) * 8;
    dst = w1p + s * 8;
  } else {
    int s = tid - 24576, ot = s >> 9, ks = (s >> 6) & 7, l = s & 63;
    src = r2w + (ot * 16 + (l & 15)) * 256 + ks * 32 + (l >> 4) * 8;
    dst = w2p + s * 8;
  }
  float4 v0 = *(const float4*)src;
  float4 v1 = *(const float4*)(src + 4);
  uint4 pk;
  pk.x = f2bf(v0.x) | (f2bf(v0.y) << 16);
  pk.y = f2bf(v0.z) | (f2bf(v0.w) << 16);
  pk.z = f2bf(v1.x) | (f2bf(v1.y) << 16);
  pk.w = f2bf(v1.z) | (f2bf(v1.w) << 16);
  *(uint4*)dst = pk;
}

// ---------------- y = mean(masked x, axis=(2,3)), float4 ----------------
__global__ void k_ymean(const float* __restrict__ x, const float* __restrict__ keep,
                        float* __restrict__ y) {
  int bc = blockIdx.x;
  int b = bc >> 8, c = bc & 255;
  const float4* row = (const float4*)(x + (size_t)bc * HW);
  int t = threadIdx.x;
  float s = 0.f;
  for (int q = t; q < HW / 4; q += 256) {
    float4 v = row[q];
    uint32_t base = (uint32_t)((b * HW + q * 4) * 256 + c);
    s += v.x * keep[base / 368u];
    s += v.y * keep[(base + 256u) / 368u];
    s += v.z * keep[(base + 512u) / 368u];
    s += v.w * keep[(base + 768u) / 368u];
  }
  for (int off = 32; off > 0; off >>= 1) s += __shfl_down(s, off);
  __shared__ float w4[4];
  if ((t & 63) == 0) w4[t >> 6] = s;
  __syncthreads();
  if (t == 0) y[bc] = (w4[0] + w4[1] + w4[2] + w4[3]) * (1.0f / HW);
}

// ---------------- scores -> per-(b,c) mask ----------------
__global__ void k_scores(const float* __restrict__ y, const float* __restrict__ fc1,
                         const float* __restrict__ fc2, const float* __restrict__ thr,
                         const float* __restrict__ aw, const int* __restrict__ plr,
                         float* __restrict__ maskv) {
  int b = blockIdx.x, t = threadIdx.x;
  __shared__ float ysh[256];
  __shared__ float hsh[16];
  ysh[t] = y[b * 256 + t];
  __syncthreads();
  if (t < 16) {
    float a = 0.f;
    for (int c = 0; c < 256; ++c) a += ysh[c] * fc1[t * 256 + c];
    hsh[t] = fmaxf(a, 0.f);
  }
  __syncthreads();
  float s = 0.f;
  #pragma unroll
  for (int j = 0; j < 16; ++j) s += hsh[j] * fc2[t * 16 + j];
  float sc = 1.f / (1.f + expf(-s));
  float m = sc + (float)plr[0] * aw[t] - thr[0];
  maskv[b * 256 + t] = fmaxf(m, 0.f);
}

// ---------------- fused main chain: bf16 MFMA (8 waves, 4ch-group x 2px-half) ----------------
// fragment-linear LDS: element (c,p) at ((c>>5)*4+(p>>4))*512 + ((p&15)+16*((c&31)>>3))*8 + (c&7)
// Wave w: g = w>>1 owns channels [g*64, g*64+64) (A-tiles 4g..4g+3);
//         h = w&1 owns pixel half nt in {2h, 2h+1}.
// Each B-frag read feeds 4 MFMAs -> LDS read traffic halved vs R0.
__global__ __launch_bounds__(512, 4) void k_main(
    const float* __restrict__ x, const float* __restrict__ keep,
    const ushort* __restrict__ wdp, const ushort* __restrict__ w1p,
    const ushort* __restrict__ w2p, const float* __restrict__ maskv,
    float* __restrict__ out) {
  __shared__ __align__(16) short XT[16384];   // 32 KB
  __shared__ __align__(16) short ST[16384];   // 32 KB
  int tile = blockIdx.x;
  int bb = tile / 49, hw0 = (tile % 49) * 64;
  int t = threadIdx.x;
  int lane = t & 63, w = t >> 6;
  int l15 = lane & 15, lhi = lane >> 4;
  int g = w >> 1, h = w & 1;

  // ---- stage masked x tile as bf16 fragments: wave w = channels w*32..w*32+31 ----
  {
    const float* xb = x + (size_t)bb * (Cch * HW);
    uint32_t pixb = (uint32_t)(bb * HW + hw0);
    int p = lane;
    uint32_t ia0 = (pixb + (uint32_t)p) * 256u;
    uint32_t k0 = ia0 / 368u;
    uint32_t cstar = 368u * (k0 + 1u) - ia0;   // channels >= cstar use chunk k0+1
    float kp0 = keep[k0];
    float kp1 = keep[k0 + 1];
    const float* xcol = xb + hw0 + p;
    int c0 = w * 32;
    #pragma unroll
    for (int k = 0; k < 4; ++k) {
      uint32_t pw0, pw1, pw2, pw3;
      #pragma unroll
      for (int hh = 0; hh < 4; ++hh) {
        uint32_t ca = (uint32_t)(c0 + k * 8 + hh * 2);
        float va = xcol[(size_t)ca * HW] * (ca < cstar ? kp0 : kp1);
        float vb = xcol[(size_t)(ca + 1u) * HW] * ((ca + 1u) < cstar ? kp0 : kp1);
        uint32_t pkv = cvtpk(va, vb);
        if (hh == 0) pw0 = pkv; else if (hh == 1) pw1 = pkv;
        else if (hh == 2) pw2 = pkv; else pw3 = pkv;
      }
      uint4 pk; pk.x = pw0; pk.y = pw1; pk.z = pw2; pk.w = pw3;
      *(uint4*)&XT[(w * 4 + (p >> 4)) * 512 + ((p & 15) + 16 * k) * 8] = pk;
    }
  }
  __syncthreads();

  f32x4 zero4 = {0.f, 0.f, 0.f, 0.f};
  f32x4 acc[4][2];
  int row16a = (lhi >> 1);
  int sub4 = (lhi & 1) * 4;

  // ======== det = Wd @ x ========
  #pragma unroll
  for (int mt = 0; mt < 4; ++mt)
    #pragma unroll
    for (int n2 = 0; n2 < 2; ++n2) acc[mt][n2] = zero4;
  {
    const ushort* ap = wdp + (size_t)(g * 32) * 512 + lane * 8;   // tile stride 8*512
    bf16x8 a[4], na[4];
    #pragma unroll
    for (int mt = 0; mt < 4; ++mt) a[mt] = *(const bf16x8*)(ap + (size_t)mt * 8 * 512);
    #pragma unroll
    for (int ks = 0; ks < 8; ++ks) {
      #pragma unroll
      for (int mt = 0; mt < 4; ++mt)
        na[mt] = (ks < 7) ? *(const bf16x8*)(ap + (size_t)(mt * 8 + ks + 1) * 512) : a[mt];
      #pragma unroll
      for (int n2 = 0; n2 < 2; ++n2) {
        bf16x8 b = *(const bf16x8*)&XT[(ks * 4 + 2 * h + n2) * 512 + lane * 8];
        #pragma unroll
        for (int mt = 0; mt < 4; ++mt)
          acc[mt][n2] = __builtin_amdgcn_mfma_f32_16x16x32_bf16(a[mt], b, acc[mt][n2], 0, 0, 0);
      }
      #pragma unroll
      for (int mt = 0; mt < 4; ++mt) a[mt] = na[mt];
    }
  }

  // ---- st = sigmoid(det) * x -> ST (XT untouched; no barrier needed) ----
  #pragma unroll
  for (int mt = 0; mt < 4; ++mt) {
    int cg32 = 2 * g + (mt >> 1);
    int row16 = (mt & 1) * 2 + row16a;
    #pragma unroll
    for (int n2 = 0; n2 < 2; ++n2) {
      int nt = 2 * h + n2;
      int off = (cg32 * 4 + nt) * 512 + (l15 + 16 * row16) * 8 + sub4;
      ushort4 xv = *(const ushort4*)&XT[off];
      float s0 = bf2f(xv.x) / (1.f + __expf(-acc[mt][n2][0]));
      float s1 = bf2f(xv.y) / (1.f + __expf(-acc[mt][n2][1]));
      float s2 = bf2f(xv.z) / (1.f + __expf(-acc[mt][n2][2]));
      float s3 = bf2f(xv.w) / (1.f + __expf(-acc[mt][n2][3]));
      uint2 sv;
      sv.x = cvtpk(s0, s1);
      sv.y = cvtpk(s2, s3);
      *(uint2*)&ST[off] = sv;
    }
  }
  __syncthreads();

  // ======== r1 = relu(W1 @ [x; st]) ========
  f32x4 acc2[4][2];
  #pragma unroll
  for (int mt = 0; mt < 4; ++mt)
    #pragma unroll
    for (int n2 = 0; n2 < 2; ++n2) acc2[mt][n2] = zero4;
  {
    const ushort* ap = w1p + (size_t)(g * 64) * 512 + lane * 8;   // tile stride 16*512
    bf16x8 a[4], na[4];
    #pragma unroll
    for (int mt = 0; mt < 4; ++mt) a[mt] = *(const bf16x8*)(ap + (size_t)mt * 16 * 512);
    #pragma unroll
    for (int ks = 0; ks < 16; ++ks) {
      #pragma unroll
      for (int mt = 0; mt < 4; ++mt)
        na[mt] = (ks < 15) ? *(const bf16x8*)(ap + (size_t)(mt * 16 + ks + 1) * 512) : a[mt];
      const short* bsrc = (ks < 8) ? &XT[(ks * 4) * 512] : &ST[((ks - 8) * 4) * 512];
      #pragma unroll
      for (int n2 = 0; n2 < 2; ++n2) {
        bf16x8 b = *(const bf16x8*)&bsrc[(2 * h + n2) * 512 + lane * 8];
        #pragma unroll
        for (int mt = 0; mt < 4; ++mt)
          acc2[mt][n2] = __builtin_amdgcn_mfma_f32_16x16x32_bf16(a[mt], b, acc2[mt][n2], 0, 0, 0);
      }
      #pragma unroll
      for (int mt = 0; mt < 4; ++mt) a[mt] = na[mt];
    }
  }
  __syncthreads();   // all rec1 LDS reads complete before overwriting XT

  // ---- write r1 = relu(acc2) into XT ----
  #pragma unroll
  for (int mt = 0; mt < 4; ++mt) {
    int cg32 = 2 * g + (mt >> 1);
    int row16 = (mt & 1) * 2 + row16a;
    #pragma unroll
    for (int n2 = 0; n2 < 2; ++n2) {
      int nt = 2 * h + n2;
      int off = (cg32 * 4 + nt) * 512 + (l15 + 16 * row16) * 8 + sub4;
      uint2 rv;
      rv.x = cvtpk(fmaxf(acc2[mt][n2][0], 0.f), fmaxf(acc2[mt][n2][1], 0.f));
      rv.y = cvtpk(fmaxf(acc2[mt][n2][2], 0.f), fmaxf(acc2[mt][n2][3], 0.f));
      *(uint2*)&XT[off] = rv;
    }
  }
  __syncthreads();

  // ======== out = (W2 @ r1) * mask ========
  #pragma unroll
  for (int mt = 0; mt < 4; ++mt)
    #pragma unroll
    for (int n2 = 0; n2 < 2; ++n2) acc[mt][n2] = zero4;
  {
    const ushort* ap = w2p + (size_t)(g * 32) * 512 + lane * 8;   // tile stride 8*512
    bf16x8 a[4], na[4];
    #pragma unroll
    for (int mt = 0; mt < 4; ++mt) a[mt] = *(const bf16x8*)(ap + (size_t)mt * 8 * 512);
    #pragma unroll
    for (int ks = 0; ks < 8; ++ks) {
      #pragma unroll
      for (int mt = 0; mt < 4; ++mt)
        na[mt] = (ks < 7) ? *(const bf16x8*)(ap + (size_t)(mt * 8 + ks + 1) * 512) : a[mt];
      #pragma unroll
      for (int n2 = 0; n2 < 2; ++n2) {
        bf16x8 b = *(const bf16x8*)&XT[(ks * 4 + 2 * h + n2) * 512 + lane * 8];
        #pragma unroll
        for (int mt = 0; mt < 4; ++mt)
          acc[mt][n2] = __builtin_amdgcn_mfma_f32_16x16x32_bf16(a[mt], b, acc[mt][n2], 0, 0, 0);
      }
      #pragma unroll
      for (int mt = 0; mt < 4; ++mt) a[mt] = na[mt];
    }
  }

  // ---- final: scale by mask, store fp32 ----
  #pragma unroll
  for (int mt = 0; mt < 4; ++mt)
    #pragma unroll
    for (int r = 0; r < 4; ++r) {
      int o = g * 64 + mt * 16 + 4 * lhi + r;
      float m = maskv[bb * 256 + o];
      float* orow = out + (size_t)(bb * 256 + o) * HW + hw0;
      #pragma unroll
      for (int n2 = 0; n2 < 2; ++n2)
        orow[(2 * h + n2) * 16 + l15] = acc[mt][n2][r] * m;
    }
}

extern "C" void kernel_launch(void* const* d_in, const int* in_sizes, int n_in,
                              void* d_out, int out_size, void* d_ws, size_t ws_size,
                              hipStream_t stream) {
  const float* x   = (const float*)d_in[0];
  const float* fc1 = (const float*)d_in[1];
  const float* fc2 = (const float*)d_in[2];
  const float* thr = (const float*)d_in[3];
  const float* dw  = (const float*)d_in[4];
  const float* r1w = (const float*)d_in[5];
  const float* r2w = (const float*)d_in[6];
  const float* aw  = (const float*)d_in[7];
  const int*   plr = (const int*)d_in[8];

  float*    out = (float*)d_out;
  uint32_t* ob  = (uint32_t*)d_out;
  float*    ws  = (float*)d_ws;

  uint64_t* sc1   = (uint64_t*)(ob + SC1_W);
  uint64_t* sc2   = (uint64_t*)(ob + SC2_W);
  uint32_t* bits1 = ob + BITS1_W;
  uint32_t* bits2 = ob + BITS2_W;
  uint32_t* rk1   = ob + R1_W;
  uint32_t* rk2   = ob + R2_W;
  uint32_t* hist1 = ob + HIST1_W;
  uint32_t* pre1  = ob + PRE1_W;
  uint32_t* cnt1  = ob + CNT1_W;
  uint32_t* hist2 = ob + HIST2_W;
  uint32_t* pre2  = ob + PRE2_W;
  uint32_t* cnt2  = ob + CNT2_W;
  float*    yv    = (float*)(ob + Y_W);

  float*  keep  = ws + KEEP_W;
  float*  maskv = ws + MASKV_W;
  ushort* wdp   = (ushort*)(ws + WPACK_W);
  ushort* w1p   = wdp + 65536;
  ushort* w2p   = w1p + 131072;

  hipMemsetAsync((void*)(ob + HIST1_W), 0, (size_t)6 * NB2 * 4, stream);

  dim3 blk(256);
  k_bits<<<273, blk, 0, stream>>>(bits1, bits2, hist1, hist2);
  k_scan2<<<2, 1024, 0, stream>>>(hist1, pre1, hist2, pre2);
  k_scatter2<<<546, blk, 0, stream>>>(bits1, pre1, cnt1, sc1,
                                      bits2, pre2, cnt2, sc2);
  k_rank2<<<546, blk, 0, stream>>>(bits1, pre1, hist1, sc1, rk1,
                                   bits2, pre2, hist2, sc2, rk2);
  k_keepwpack<<<401, blk, 0, stream>>>(rk1, rk2, plr, keep, dw, r1w, r2w,
                                       wdp, w1p, w2p);
  k_ymean<<<8192, blk, 0, stream>>>(x, keep, yv);
  k_scores<<<32, blk, 0, stream>>>(yv, fc1, fc2, thr, aw, plr, maskv);
  k_main<<<1568, 512, 0, stream>>>(x, keep, wdp, w1p, w2p, maskv, out);
}

// Round 6
// 149.027 us; speedup vs baseline: 6.0876x; 1.0895x over previous
//
#include <hip/hip_runtime.h>
#include <stdint.h>

#define PARTITIONABLE 1

typedef float f32x4 __attribute__((ext_vector_type(4)));
typedef short bf16x8 __attribute__((ext_vector_type(8)));

namespace {
constexpr int Hh = 56, Ww = 56;
constexpr int HW = Hh * Ww;            // 3136
constexpr int Bsz = 32, Cch = 256;
constexpr int NCH = 69811;             // ceil(25690112*4/1472)
constexpr int HALF = 34906;
constexpr int NB2 = 4096;              // rank buckets (top 12 bits)

// ---- d_out scratch layout (u32 word offsets; consumed before final write) ----
constexpr int SC1_W   = 0;             // u64 x 69824
constexpr int SC2_W   = 139648;
constexpr int BITS1_W = 279296;
constexpr int BITS2_W = 349120;
constexpr int R1_W    = 418944;
constexpr int R2_W    = 488768;
constexpr int HIST1_W = 558592;        // 4096 each, 6 arrays contiguous
constexpr int PRE1_W  = 562688;
constexpr int CNT1_W  = 566784;
constexpr int HIST2_W = 570880;
constexpr int PRE2_W  = 574976;
constexpr int CNT2_W  = 579072;
constexpr int Y_W     = 583168;        // 8192 floats

// ---- d_ws layout ----
constexpr int KEEP_W  = 0;             // 69824 floats
constexpr int MASKV_W = 69824;         // 8192 floats
constexpr int WPACK_W = 78016;         // then bf16 packed weights (ushort)
}

// ---------------- threefry-2x32 (JAX-compatible) ----------------
__host__ __device__ constexpr uint32_t rotl32(uint32_t v, int r) {
  return (v << r) | (v >> (32 - r));
}
__host__ __device__ constexpr uint64_t tf2x32(uint32_t k0, uint32_t k1,
                                              uint32_t x0, uint32_t x1) {
  uint32_t ks2 = k0 ^ k1 ^ 0x1BD11BDAu;
  x0 += k0; x1 += k1;
  {const int R[4]={13,15,26,6};  for(int i=0;i<4;i++){x0+=x1;x1=rotl32(x1,R[i]);x1^=x0;}}
  x0 += k1;  x1 += ks2 + 1u;
  {const int R[4]={17,29,16,24}; for(int i=0;i<4;i++){x0+=x1;x1=rotl32(x1,R[i]);x1^=x0;}}
  x0 += ks2; x1 += k0 + 2u;
  {const int R[4]={13,15,26,6};  for(int i=0;i<4;i++){x0+=x1;x1=rotl32(x1,R[i]);x1^=x0;}}
  x0 += k0;  x1 += k1 + 3u;
  {const int R[4]={17,29,16,24}; for(int i=0;i<4;i++){x0+=x1;x1=rotl32(x1,R[i]);x1^=x0;}}
  x0 += k1;  x1 += ks2 + 4u;
  {const int R[4]={13,15,26,6};  for(int i=0;i<4;i++){x0+=x1;x1=rotl32(x1,R[i]);x1^=x0;}}
  x0 += ks2; x1 += k0 + 5u;
  return ((uint64_t)x0 << 32) | x1;
}

#if PARTITIONABLE
constexpr uint64_t KEY1 = tf2x32(0u, 1234u, 0u, 0u);
constexpr uint64_t SUB1 = tf2x32(0u, 1234u, 0u, 1u);
constexpr uint64_t SUB2 = tf2x32((uint32_t)(KEY1 >> 32), (uint32_t)KEY1, 0u, 1u);
constexpr uint32_t S1H = (uint32_t)(SUB1 >> 32), S1L = (uint32_t)SUB1;
constexpr uint32_t S2H = (uint32_t)(SUB2 >> 32), S2L = (uint32_t)SUB2;
#else
constexpr uint64_t E0 = tf2x32(0u, 1234u, 0u, 2u);
constexpr uint64_t E1 = tf2x32(0u, 1234u, 1u, 3u);
constexpr uint32_t K1H = (uint32_t)(E0 >> 32), K1L = (uint32_t)(E1 >> 32);
constexpr uint64_t F0 = tf2x32(K1H, K1L, 0u, 2u);
constexpr uint64_t F1 = tf2x32(K1H, K1L, 1u, 3u);
constexpr uint32_t S1H = (uint32_t)E0, S1L = (uint32_t)E1;
constexpr uint32_t S2H = (uint32_t)F0, S2L = (uint32_t)F1;
#endif

__device__ __forceinline__ uint32_t rnd_bits(uint32_t kh, uint32_t kl, uint32_t i) {
#if PARTITIONABLE
  uint64_t r = tf2x32(kh, kl, 0u, i);
  return (uint32_t)(r >> 32) ^ (uint32_t)r;
#else
  if (i < (uint32_t)HALF) {
    uint32_t x1 = (i + HALF < (uint32_t)NCH) ? i + HALF : 0u;
    return (uint32_t)(tf2x32(kh, kl, i, x1) >> 32);
  } else {
    return (uint32_t)tf2x32(kh, kl, i - HALF, i);
  }
#endif
}

// ---------------- bf16 helpers ----------------
__device__ __forceinline__ uint32_t f2bf(float f) {   // manual RNE (wpack path)
  uint32_t u = __float_as_uint(f);
  return (u + 0x7FFFu + ((u >> 16) & 1u)) >> 16;
}
__device__ __forceinline__ float bf2f(uint32_t h) {
  return __uint_as_float(h << 16);
}
// single-instruction packed f32x2 -> bf16x2 (RNE), gfx950
__device__ __forceinline__ uint32_t cvtpk(float lo, float hi) {
  uint32_t r;
  asm("v_cvt_pk_bf16_f32 %0, %1, %2" : "=v"(r) : "v"(lo), "v"(hi));
  return r;
}

// ---------------- mask pipeline ----------------
__global__ void k_bits(uint32_t* bits1, uint32_t* bits2,
                       uint32_t* hist1, uint32_t* hist2) {
  int i = blockIdx.x * 256 + threadIdx.x;
  if (i >= NCH) return;
  uint32_t b1 = rnd_bits(S1H, S1L, (uint32_t)i);
  uint32_t b2 = rnd_bits(S2H, S2L, (uint32_t)i);
  bits1[i] = b1; bits2[i] = b2;
  atomicAdd(&hist1[b1 >> 20], 1u);
  atomicAdd(&hist2[b2 >> 20], 1u);
}

// both scans in one launch: block 0 -> (h1,p1), block 1 -> (h2,p2)
__global__ __launch_bounds__(1024) void k_scan2(const uint32_t* h1, uint32_t* p1o,
                                                const uint32_t* h2, uint32_t* p2o) {
  const uint32_t* h = blockIdx.x ? h2 : h1;
  uint32_t* pre = blockIdx.x ? p2o : p1o;
  __shared__ uint32_t part[1024];
  int t = threadIdx.x;
  uint4 v = *(const uint4*)&h[t * 4];
  uint32_t s = v.x + v.y + v.z + v.w;
  part[t] = s;
  __syncthreads();
  for (int off = 1; off < 1024; off <<= 1) {
    uint32_t u = (t >= off) ? part[t - off] : 0u;
    __syncthreads();
    part[t] += u;
    __syncthreads();
  }
  uint32_t run = part[t] - s;
  uint4 o;
  o.x = run; o.y = run + v.x; o.z = o.y + v.y; o.w = o.z + v.z;
  *(uint4*)&pre[t * 4] = o;
}

__global__ void k_scatter2(const uint32_t* bits1, const uint32_t* pre1,
                           uint32_t* cnt1, uint64_t* sc1,
                           const uint32_t* bits2, const uint32_t* pre2,
                           uint32_t* cnt2, uint64_t* sc2) {
  int blk = blockIdx.x;
  bool second = blk >= 273;
  const uint32_t* bits = second ? bits2 : bits1;
  const uint32_t* pre  = second ? pre2  : pre1;
  uint32_t* cnt = second ? cnt2 : cnt1;
  uint64_t* sc  = second ? sc2  : sc1;
  int i = (second ? blk - 273 : blk) * 256 + threadIdx.x;
  if (i >= NCH) return;
  uint32_t b = bits[i], bk = b >> 20;
  uint32_t pos = pre[bk] + atomicAdd(&cnt[bk], 1u);
  sc[pos] = ((uint64_t)b << 32) | (uint32_t)i;
}

__global__ void k_rank2(const uint32_t* bits1, const uint32_t* pre1,
                        const uint32_t* hist1, const uint64_t* sc1, uint32_t* rk1,
                        const uint32_t* bits2, const uint32_t* pre2,
                        const uint32_t* hist2, const uint64_t* sc2, uint32_t* rk2) {
  int blk = blockIdx.x;
  bool second = blk >= 273;
  const uint32_t* bits = second ? bits2 : bits1;
  const uint32_t* pre  = second ? pre2  : pre1;
  const uint32_t* hist = second ? hist2 : hist1;
  const uint64_t* sc   = second ? sc2   : sc1;
  uint32_t* rnk = second ? rk2 : rk1;
  int i = (second ? blk - 273 : blk) * 256 + threadIdx.x;
  if (i >= NCH) return;
  uint32_t b = bits[i], bk = b >> 20;
  uint32_t s = pre[bk], n = hist[bk];
  uint64_t my = ((uint64_t)b << 32) | (uint32_t)i;
  uint32_t c = 0;
  for (uint32_t k = 0; k < n; ++k) c += (sc[s + k] < my) ? 1u : 0u;
  rnk[i] = s + c;
}

// keep + weight prepack fused (wpack part has no deps on rank)
__global__ void k_keepwpack(const uint32_t* r1, const uint32_t* r2,
                            const int* plr, float* keep,
                            const float* __restrict__ dw,
                            const float* __restrict__ r1w,
                            const float* __restrict__ r2w,
                            ushort* __restrict__ wdp, ushort* __restrict__ w1p,
                            ushort* __restrict__ w2p) {
  int blk = blockIdx.x;
  if (blk < 273) {
    int j = blk * 256 + threadIdx.x;
    if (j >= NCH) return;
    int L = (NCH * plr[0] + 99) / 100;
    keep[j] = (r2[r1[j]] < (uint32_t)L) ? 0.f : 1.f;
    return;
  }
  int tid = (blk - 273) * 256 + threadIdx.x;   // 32768 slots
  const float* src;
  ushort* dst;
  if (tid < 8192) {
    int s = tid, ot = s >> 9, ks = (s >> 6) & 7, l = s & 63;
    src = dw + (ot * 16 + (l & 15)) * 256 + ks * 32 + (l >> 4) * 8;
    dst = wdp + s * 8;
  } else if (tid < 24576) {
    int s = tid - 8192, ot = s >> 10, ks = (s >> 6) & 15, l = s & 63;
    src = r1w + (ot * 16 + (l & 15)) * 512 + ks * 32 + (l >> 4) * 8;
    dst = w1p + s * 8;
  } else {
    int s = tid - 24576, ot = s >> 9, ks = (s >> 6) & 7, l = s & 63;
    src = r2w + (ot * 16 + (l & 15)) * 256 + ks * 32 + (l >> 4) * 8;
    dst = w2p + s * 8;
  }
  float4 v0 = *(const float4*)src;
  float4 v1 = *(const float4*)(src + 4);
  uint4 pk;
  pk.x = f2bf(v0.x) | (f2bf(v0.y) << 16);
  pk.y = f2bf(v0.z) | (f2bf(v0.w) << 16);
  pk.z = f2bf(v1.x) | (f2bf(v1.y) << 16);
  pk.w = f2bf(v1.z) | (f2bf(v1.w) << 16);
  *(uint4*)dst = pk;
}

// ---------------- y = mean(masked x, axis=(2,3)), float4 ----------------
__global__ void k_ymean(const float* __restrict__ x, const float* __restrict__ keep,
                        float* __restrict__ y) {
  int bc = blockIdx.x;
  int b = bc >> 8, c = bc & 255;
  const float4* row = (const float4*)(x + (size_t)bc * HW);
  int t = threadIdx.x;
  float s = 0.f;
  for (int q = t; q < HW / 4; q += 256) {
    float4 v = row[q];
    uint32_t base = (uint32_t)((b * HW + q * 4) * 256 + c);
    s += v.x * keep[base / 368u];
    s += v.y * keep[(base + 256u) / 368u];
    s += v.z * keep[(base + 512u) / 368u];
    s += v.w * keep[(base + 768u) / 368u];
  }
  for (int off = 32; off > 0; off >>= 1) s += __shfl_down(s, off);
  __shared__ float w4[4];
  if ((t & 63) == 0) w4[t >> 6] = s;
  __syncthreads();
  if (t == 0) y[bc] = (w4[0] + w4[1] + w4[2] + w4[3]) * (1.0f / HW);
}

// ---------------- scores -> per-(b,c) mask ----------------
__global__ void k_scores(const float* __restrict__ y, const float* __restrict__ fc1,
                         const float* __restrict__ fc2, const float* __restrict__ thr,
                         const float* __restrict__ aw, const int* __restrict__ plr,
                         float* __restrict__ maskv) {
  int b = blockIdx.x, t = threadIdx.x;
  __shared__ float ysh[256];
  __shared__ float hsh[16];
  ysh[t] = y[b * 256 + t];
  __syncthreads();
  if (t < 16) {
    float a = 0.f;
    for (int c = 0; c < 256; ++c) a += ysh[c] * fc1[t * 256 + c];
    hsh[t] = fmaxf(a, 0.f);
  }
  __syncthreads();
  float s = 0.f;
  #pragma unroll
  for (int j = 0; j < 16; ++j) s += hsh[j] * fc2[t * 16 + j];
  float sc = 1.f / (1.f + expf(-s));
  float m = sc + (float)plr[0] * aw[t] - thr[0];
  maskv[b * 256 + t] = fmaxf(m, 0.f);
}

// ---------------- fused main chain: bf16 MFMA (R0 2A x 4B partition + batched A) ----------------
// fragment-linear LDS: element (c,p) at ((c>>5)*4+(p>>4))*512 + ((p&15)+16*((c&31)>>3))*8 + (c&7)
// A-fragments are preloaded in 16-wide bursts (64 VGPRs) so the K-loops are pure LDS+MFMA;
// one vmcnt drain per batch instead of 8 partially-hidden L2-latency stalls.
__global__ __launch_bounds__(512, 4) void k_main(
    const float* __restrict__ x, const float* __restrict__ keep,
    const ushort* __restrict__ wdp, const ushort* __restrict__ w1p,
    const ushort* __restrict__ w2p, const float* __restrict__ maskv,
    float* __restrict__ out) {
  __shared__ __align__(16) short XT[16384];   // 32 KB
  __shared__ __align__(16) short ST[16384];   // 32 KB
  int tile = blockIdx.x;
  int bb = tile / 49, hw0 = (tile % 49) * 64;
  int t = threadIdx.x;
  int lane = t & 63, w = t >> 6;
  int l15 = lane & 15, lhi = lane >> 4;

  // ---- stage masked x tile as bf16 fragments: wave w = channels w*32..w*32+31 ----
  {
    const float* xb = x + (size_t)bb * (Cch * HW);
    uint32_t pixb = (uint32_t)(bb * HW + hw0);
    int p = lane;
    uint32_t ia0 = (pixb + (uint32_t)p) * 256u;
    uint32_t k0 = ia0 / 368u;
    uint32_t cstar = 368u * (k0 + 1u) - ia0;   // channels >= cstar use chunk k0+1
    float kp0 = keep[k0];
    float kp1 = keep[k0 + 1];
    const float* xcol = xb + hw0 + p;
    int c0 = w * 32;
    #pragma unroll
    for (int k = 0; k < 4; ++k) {
      uint32_t pw0, pw1, pw2, pw3;
      #pragma unroll
      for (int h = 0; h < 4; ++h) {
        uint32_t ca = (uint32_t)(c0 + k * 8 + h * 2);
        float va = xcol[(size_t)ca * HW] * (ca < cstar ? kp0 : kp1);
        float vb = xcol[(size_t)(ca + 1u) * HW] * ((ca + 1u) < cstar ? kp0 : kp1);
        uint32_t pkv = cvtpk(va, vb);
        if (h == 0) pw0 = pkv; else if (h == 1) pw1 = pkv;
        else if (h == 2) pw2 = pkv; else pw3 = pkv;
      }
      uint4 pk; pk.x = pw0; pk.y = pw1; pk.z = pw2; pk.w = pw3;
      *(uint4*)&XT[(w * 4 + (p >> 4)) * 512 + ((p & 15) + 16 * k) * 8] = pk;
    }
  }
  __syncthreads();

  f32x4 zero4 = {0.f, 0.f, 0.f, 0.f};
  f32x4 acc[2][4];
  int row16a = (lhi >> 1);                // epilogue row helper
  int sub4 = (lhi & 1) * 4;

  // ======== det = Wd @ x ========
  #pragma unroll
  for (int mt = 0; mt < 2; ++mt)
    #pragma unroll
    for (int nt = 0; nt < 4; ++nt) acc[mt][nt] = zero4;
  {
    const ushort* a0p = wdp + ((w * 2 + 0) * 8) * 512 + lane * 8;
    const ushort* a1p = wdp + ((w * 2 + 1) * 8) * 512 + lane * 8;
    bf16x8 A0[8], A1[8];
    #pragma unroll
    for (int k = 0; k < 8; ++k) {
      A0[k] = *(const bf16x8*)(a0p + k * 512);
      A1[k] = *(const bf16x8*)(a1p + k * 512);
    }
    #pragma unroll
    for (int ks = 0; ks < 8; ++ks) {
      #pragma unroll
      for (int nt = 0; nt < 4; ++nt) {
        bf16x8 b = *(const bf16x8*)&XT[(ks * 4 + nt) * 512 + lane * 8];
        acc[0][nt] = __builtin_amdgcn_mfma_f32_16x16x32_bf16(A0[ks], b, acc[0][nt], 0, 0, 0);
        acc[1][nt] = __builtin_amdgcn_mfma_f32_16x16x32_bf16(A1[ks], b, acc[1][nt], 0, 0, 0);
      }
    }
  }

  // ---- st = sigmoid(det) * x  (XT untouched; no barrier needed) ----
  #pragma unroll
  for (int mt = 0; mt < 2; ++mt) {
    int row16 = mt * 2 + row16a;
    #pragma unroll
    for (int nt = 0; nt < 4; ++nt) {
      int off = (w * 4 + nt) * 512 + (l15 + 16 * row16) * 8 + sub4;
      ushort4 xv = *(const ushort4*)&XT[off];
      float s0 = bf2f(xv.x) / (1.f + __expf(-acc[mt][nt][0]));
      float s1 = bf2f(xv.y) / (1.f + __expf(-acc[mt][nt][1]));
      float s2 = bf2f(xv.z) / (1.f + __expf(-acc[mt][nt][2]));
      float s3 = bf2f(xv.w) / (1.f + __expf(-acc[mt][nt][3]));
      uint2 sv;
      sv.x = cvtpk(s0, s1);
      sv.y = cvtpk(s2, s3);
      *(uint2*)&ST[off] = sv;
    }
  }
  __syncthreads();

  // ======== r1 = relu(W1 @ [x; st]) ======== (two 16-fragment A batches)
  f32x4 acc2[2][4];
  #pragma unroll
  for (int mt = 0; mt < 2; ++mt)
    #pragma unroll
    for (int nt = 0; nt < 4; ++nt) acc2[mt][nt] = zero4;
  {
    const ushort* a0p = w1p + ((w * 2 + 0) * 16) * 512 + lane * 8;
    const ushort* a1p = w1p + ((w * 2 + 1) * 16) * 512 + lane * 8;
    bf16x8 A0[8], A1[8];
    // half 1: ks 0..7 (B from XT)
    #pragma unroll
    for (int k = 0; k < 8; ++k) {
      A0[k] = *(const bf16x8*)(a0p + k * 512);
      A1[k] = *(const bf16x8*)(a1p + k * 512);
    }
    #pragma unroll
    for (int ks = 0; ks < 8; ++ks) {
      #pragma unroll
      for (int nt = 0; nt < 4; ++nt) {
        bf16x8 b = *(const bf16x8*)&XT[(ks * 4 + nt) * 512 + lane * 8];
        acc2[0][nt] = __builtin_amdgcn_mfma_f32_16x16x32_bf16(A0[ks], b, acc2[0][nt], 0, 0, 0);
        acc2[1][nt] = __builtin_amdgcn_mfma_f32_16x16x32_bf16(A1[ks], b, acc2[1][nt], 0, 0, 0);
      }
    }
    // half 2: ks 8..15 (B from ST)
    #pragma unroll
    for (int k = 0; k < 8; ++k) {
      A0[k] = *(const bf16x8*)(a0p + (k + 8) * 512);
      A1[k] = *(const bf16x8*)(a1p + (k + 8) * 512);
    }
    #pragma unroll
    for (int ks = 0; ks < 8; ++ks) {
      #pragma unroll
      for (int nt = 0; nt < 4; ++nt) {
        bf16x8 b = *(const bf16x8*)&ST[(ks * 4 + nt) * 512 + lane * 8];
        acc2[0][nt] = __builtin_amdgcn_mfma_f32_16x16x32_bf16(A0[ks], b, acc2[0][nt], 0, 0, 0);
        acc2[1][nt] = __builtin_amdgcn_mfma_f32_16x16x32_bf16(A1[ks], b, acc2[1][nt], 0, 0, 0);
      }
    }
  }
  __syncthreads();   // all rec1 LDS reads complete before overwriting XT

  // ---- write r1 = relu(acc2) into XT ----
  #pragma unroll
  for (int mt = 0; mt < 2; ++mt) {
    int row16 = mt * 2 + row16a;
    #pragma unroll
    for (int nt = 0; nt < 4; ++nt) {
      int off = (w * 4 + nt) * 512 + (l15 + 16 * row16) * 8 + sub4;
      uint2 rv;
      rv.x = cvtpk(fmaxf(acc2[mt][nt][0], 0.f), fmaxf(acc2[mt][nt][1], 0.f));
      rv.y = cvtpk(fmaxf(acc2[mt][nt][2], 0.f), fmaxf(acc2[mt][nt][3], 0.f));
      *(uint2*)&XT[off] = rv;
    }
  }
  __syncthreads();

  // ======== out = (W2 @ r1) * mask ========
  #pragma unroll
  for (int mt = 0; mt < 2; ++mt)
    #pragma unroll
    for (int nt = 0; nt < 4; ++nt) acc[mt][nt] = zero4;
  {
    const ushort* a0p = w2p + ((w * 2 + 0) * 8) * 512 + lane * 8;
    const ushort* a1p = w2p + ((w * 2 + 1) * 8) * 512 + lane * 8;
    bf16x8 A0[8], A1[8];
    #pragma unroll
    for (int k = 0; k < 8; ++k) {
      A0[k] = *(const bf16x8*)(a0p + k * 512);
      A1[k] = *(const bf16x8*)(a1p + k * 512);
    }
    #pragma unroll
    for (int ks = 0; ks < 8; ++ks) {
      #pragma unroll
      for (int nt = 0; nt < 4; ++nt) {
        bf16x8 b = *(const bf16x8*)&XT[(ks * 4 + nt) * 512 + lane * 8];
        acc[0][nt] = __builtin_amdgcn_mfma_f32_16x16x32_bf16(A0[ks], b, acc[0][nt], 0, 0, 0);
        acc[1][nt] = __builtin_amdgcn_mfma_f32_16x16x32_bf16(A1[ks], b, acc[1][nt], 0, 0, 0);
      }
    }
  }

  // ---- final: scale by mask, store fp32 ----
  #pragma unroll
  for (int mt = 0; mt < 2; ++mt)
    #pragma unroll
    for (int r = 0; r < 4; ++r) {
      int o = w * 32 + mt * 16 + 4 * lhi + r;
      float m = maskv[bb * 256 + o];
      float* orow = out + (size_t)(bb * 256 + o) * HW + hw0;
      #pragma unroll
      for (int nt = 0; nt < 4; ++nt)
        orow[nt * 16 + l15] = acc[mt][nt][r] * m;
    }
}

extern "C" void kernel_launch(void* const* d_in, const int* in_sizes, int n_in,
                              void* d_out, int out_size, void* d_ws, size_t ws_size,
                              hipStream_t stream) {
  const float* x   = (const float*)d_in[0];
  const float* fc1 = (const float*)d_in[1];
  const float* fc2 = (const float*)d_in[2];
  const float* thr = (const float*)d_in[3];
  const float* dw  = (const float*)d_in[4];
  const float* r1w = (const float*)d_in[5];
  const float* r2w = (const float*)d_in[6];
  const float* aw  = (const float*)d_in[7];
  const int*   plr = (const int*)d_in[8];

  float*    out = (float*)d_out;
  uint32_t* ob  = (uint32_t*)d_out;
  float*    ws  = (float*)d_ws;

  uint64_t* sc1   = (uint64_t*)(ob + SC1_W);
  uint64_t* sc2   = (uint64_t*)(ob + SC2_W);
  uint32_t* bits1 = ob + BITS1_W;
  uint32_t* bits2 = ob + BITS2_W;
  uint32_t* rk1   = ob + R1_W;
  uint32_t* rk2   = ob + R2_W;
  uint32_t* hist1 = ob + HIST1_W;
  uint32_t* pre1  = ob + PRE1_W;
  uint32_t* cnt1  = ob + CNT1_W;
  uint32_t* hist2 = ob + HIST2_W;
  uint32_t* pre2  = ob + PRE2_W;
  uint32_t* cnt2  = ob + CNT2_W;
  float*    yv    = (float*)(ob + Y_W);

  float*  keep  = ws + KEEP_W;
  float*  maskv = ws + MASKV_W;
  ushort* wdp   = (ushort*)(ws + WPACK_W);
  ushort* w1p   = wdp + 65536;
  ushort* w2p   = w1p + 131072;

  hipMemsetAsync((void*)(ob + HIST1_W), 0, (size_t)6 * NB2 * 4, stream);

  dim3 blk(256);
  k_bits<<<273, blk, 0, stream>>>(bits1, bits2, hist1, hist2);
  k_scan2<<<2, 1024, 0, stream>>>(hist1, pre1, hist2, pre2);
  k_scatter2<<<546, blk, 0, stream>>>(bits1, pre1, cnt1, sc1,
                                      bits2, pre2, cnt2, sc2);
  k_rank2<<<546, blk, 0, stream>>>(bits1, pre1, hist1, sc1, rk1,
                                   bits2, pre2, hist2, sc2, rk2);
  k_keepwpack<<<401, blk, 0, stream>>>(rk1, rk2, plr, keep, dw, r1w, r2w,
                                       wdp, w1p, w2p);
  k_ymean<<<8192, blk, 0, stream>>>(x, keep, yv);
  k_scores<<<32, blk, 0, stream>>>(yv, fc1, fc2, thr, aw, plr, maskv);
  k_main<<<1568, 512, 0, stream>>>(x, keep, wdp, w1p, w2p, maskv, out);
}